// Round 9
// baseline (1114.095 us; speedup 1.0000x reference)
//
#include <hip/hip_runtime.h>
#include <math.h>

constexpr int cB = 128, cS = 256, cF = 10, cE = 40, cNH = 8, cDH = 5;
constexpr int cI = 128, cMDH = 16, cK = 4;

// broadcast lane (group_base + l) to all 8 lanes of the group (groups of 8 within 32-lane halves)
#define BC8(v, l) __uint_as_float(__builtin_amdgcn_ds_swizzle(__float_as_uint(v), ((l) << 5) | 0x18))

// ---------------- h = x @ in_w.T + in_b + pos_encoding ----------------
__global__ __launch_bounds__(256) void init_k(const float* __restrict__ x, const float* __restrict__ w,
                                              const float* __restrict__ b, float* __restrict__ h) {
    int idx = blockIdx.x * 256 + threadIdx.x;     // B*S*E
    int e = idx % cE; int bs = idx / cE; int s = bs % cS;
    float acc = b[e];
    const float* xr = x + (size_t)bs * cF;
#pragma unroll
    for (int f = 0; f < cF; ++f) acc += xr[f] * w[e * cF + f];
    int i2 = e >> 1;
    float div = expf(-(float)(2 * i2) * (logf(10000.f) / 40.0f));
    float arg = (float)s * div;
    acc += (e & 1) ? cosf(arg) : sinf(arg);
    h[idx] = acc;
}

// ---------------- fused LayerNorm + up-projection (E=40 -> 256) ----------------
__global__ __launch_bounds__(256) void ln_up_k(const float* __restrict__ h, const float* __restrict__ lnw,
                                               const float* __restrict__ upw, float* __restrict__ xmz) {
    __shared__ float lnr[8][cE];
    int row0 = blockIdx.x * 8;
    int tid = threadIdx.x;
    if (tid < 8) {
        const float* r = h + (size_t)(row0 + tid) * cE;
        float mu = 0.f;
        for (int k = 0; k < cE; ++k) mu += r[k];
        mu *= (1.f / cE);
        float va = 0.f;
        for (int k = 0; k < cE; ++k) { float d = r[k] - mu; va += d * d; }
        va *= (1.f / cE);
        float rs = rsqrtf(va + 1e-5f);
        for (int k = 0; k < cE; ++k) lnr[tid][k] = (r[k] - mu) * rs * lnw[k];
    }
    __syncthreads();
    int o = tid;   // 0..255
    float acc[8] = {0, 0, 0, 0, 0, 0, 0, 0};
    for (int k = 0; k < cE; ++k) {
        float wv = upw[o * cE + k];
#pragma unroll
        for (int r = 0; r < 8; ++r) acc[r] += lnr[r][k] * wv;
    }
#pragma unroll
    for (int r = 0; r < 8; ++r) xmz[(size_t)(row0 + r) * 256 + o] = acc[r];
}

// ---------------- depthwise causal conv (K=4) + SiLU ----------------
template <int C>
__global__ __launch_bounds__(256) void conv_silu_k(const float* __restrict__ in, int instride,
                                                   const float* __restrict__ w, const float* __restrict__ bias,
                                                   float* __restrict__ out) {
    int idx = blockIdx.x * 256 + threadIdx.x;   // B*S*C
    int c = idx % C; int bs = idx / C; int s = bs % cS;
    float acc = bias[c];
#pragma unroll
    for (int j = 0; j < cK; ++j) {
        int sj = s - 3 + j;
        if (sj >= 0) acc += in[(size_t)(bs + j - 3) * instride + c] * w[c * cK + j];
    }
    float sg = 1.f / (1.f + __expf(-acc));
    out[idx] = acc * sg;
}

// ---------------- block-diagonal headwise q,k,v ----------------
__global__ __launch_bounds__(256) void qkv_k(const float* __restrict__ xc, const float* __restrict__ xmz,
                                             const float* __restrict__ qw, const float* __restrict__ kw,
                                             const float* __restrict__ vw,
                                             float* __restrict__ qb, float* __restrict__ kb, float* __restrict__ vb) {
    int idx = blockIdx.x * 256 + threadIdx.x;   // B*S*I
    int c = idx & 127; int bs = idx >> 7;
    int n = c >> 2, o = c & 3;
    const float* xcr = xc + (size_t)bs * cI + n * 4;
    const float* xmr = xmz + (size_t)bs * 256 + n * 4;
    const float* qwp = qw + n * 16 + o * 4;
    const float* kwp = kw + n * 16 + o * 4;
    const float* vwp = vw + n * 16 + o * 4;
    float aq = 0, ak = 0, av = 0;
#pragma unroll
    for (int i = 0; i < 4; ++i) { float a = xcr[i], m = xmr[i]; aq += a * qwp[i]; ak += a * kwp[i]; av += m * vwp[i]; }
    qb[idx] = aq; kb[idx] = ak; vb[idx] = av;
}

// ---------------- input/forget gate pre-activations ip, fp (B,NH,S) v2 ----------------
__global__ __launch_bounds__(128, 2) void gates_k(const float* __restrict__ qb, const float* __restrict__ kb,
                                                  const float* __restrict__ vb, const float* __restrict__ igw,
                                                  const float* __restrict__ igb, const float* __restrict__ fgw,
                                                  const float* __restrict__ fgb,
                                                  float* __restrict__ ipb, float* __restrict__ fpb) {
    __shared__ float g[32 * 388];
    __shared__ float w[16 * 388];
    int row0 = blockIdx.x * 32;
    int tid = threadIdx.x;

    for (int i = tid; i < 16 * 96; i += 128) {
        int r = i / 96, c4 = i - r * 96;
        const float* src = (r < 8) ? (igw + r * 384) : (fgw + (r - 8) * 384);
        *(float4*)&w[r * 388 + c4 * 4] = ((const float4*)src)[c4];
    }
    for (int i = tid; i < 32 * 96; i += 128) {
        int r = i / 96, c4 = i - r * 96;
        size_t gr = (size_t)(row0 + r) * cI;
        const float4* src = (c4 < 32) ? (const float4*)(qb + gr) + c4
                          : (c4 < 64) ? (const float4*)(kb + gr) + (c4 - 32)
                                      : (const float4*)(vb + gr) + (c4 - 64);
        *(float4*)&g[r * 388 + c4 * 4] = *src;
    }
    __syncthreads();

    int rp = tid >> 3;
    int hp = tid & 7;
    int r0 = 2 * rp, r1 = r0 + 1;
    int o0 = 2 * hp, o1 = o0 + 1;

    const float4* g0p = (const float4*)(g + r0 * 388);
    const float4* g1p = (const float4*)(g + r1 * 388);
    const float4* w0p = (const float4*)(w + o0 * 388);
    const float4* w1p = (const float4*)(w + o1 * 388);

    float a00 = 0.f, a01 = 0.f, a10 = 0.f, a11 = 0.f;
#pragma unroll 4
    for (int c4 = 0; c4 < 96; ++c4) {
        float4 gv0 = g0p[c4], gv1 = g1p[c4];
        float4 wv0 = w0p[c4], wv1 = w1p[c4];
        a00 = fmaf(gv0.x, wv0.x, a00); a00 = fmaf(gv0.y, wv0.y, a00);
        a00 = fmaf(gv0.z, wv0.z, a00); a00 = fmaf(gv0.w, wv0.w, a00);
        a01 = fmaf(gv0.x, wv1.x, a01); a01 = fmaf(gv0.y, wv1.y, a01);
        a01 = fmaf(gv0.z, wv1.z, a01); a01 = fmaf(gv0.w, wv1.w, a01);
        a10 = fmaf(gv1.x, wv0.x, a10); a10 = fmaf(gv1.y, wv0.y, a10);
        a10 = fmaf(gv1.z, wv0.z, a10); a10 = fmaf(gv1.w, wv0.w, a10);
        a11 = fmaf(gv1.x, wv1.x, a11); a11 = fmaf(gv1.y, wv1.y, a11);
        a11 = fmaf(gv1.z, wv1.z, a11); a11 = fmaf(gv1.w, wv1.w, a11);
    }

    int h0 = o0 & 7, wch0 = o0 >> 3;
    int h1 = o1 & 7, wch1 = o1 >> 3;
    float b0 = wch0 ? fgb[h0] : igb[h0];
    float b1 = wch1 ? fgb[h1] : igb[h1];
    int grow0 = row0 + r0, grow1 = row0 + r1;
    int bb0 = grow0 >> 8, ss0 = grow0 & 255;
    int bb1 = grow1 >> 8, ss1 = grow1 & 255;
    float* d00 = (wch0 ? fpb : ipb) + (size_t)(bb0 * cNH + h0) * cS + ss0;
    float* d01 = (wch1 ? fpb : ipb) + (size_t)(bb0 * cNH + h1) * cS + ss0;
    float* d10 = (wch0 ? fpb : ipb) + (size_t)(bb1 * cNH + h0) * cS + ss1;
    float* d11 = (wch1 ? fpb : ipb) + (size_t)(bb1 * cNH + h1) * cS + ss1;
    *d00 = a00 + b0; *d01 = a01 + b1; *d10 = a10 + b0; *d11 = a11 + b1;
}

// ---------------- fused mLSTM attention v5: 4 waves per (b,h) ----------------
// Same LDS footprint/traffic as v3 (each t read by exactly one wave) but 4 waves
// per block -> ~3 waves/SIMD resident: the ds_read->FMA dependency stalls that
// capped v3/v4 at ~90us get hidden by cross-wave issue. qreg pre-scaled by
// 0.25*exp(-Mx[s]) so the hot loop is ccf = qk * sEA[t]. Reduction: staged LDS
// spills into dead sKf/sVf.
__global__ __launch_bounds__(256, 3) void attn_k(const float* __restrict__ qg, const float* __restrict__ kg,
                                                 const float* __restrict__ vg, const float* __restrict__ ipg,
                                                 const float* __restrict__ fpg, float* __restrict__ hatt) {
    int bh = blockIdx.x; int b = bh >> 3, h = bh & 7;
    int tid = threadIdx.x;
    int wid = tid >> 6, lane = tid & 63;
    __shared__ float sEA[cS], sMx[cS], sFc[cS];
    __shared__ float sKf[cS * cMDH], sVf[cS * cMDH];

    // --- gate scans (each wave computes redundantly; identical values) ---
    const float4 fp4 = ((const float4*)(fpg + (size_t)bh * cS))[lane];
    const float4 ip4 = ((const float4*)(ipg + (size_t)bh * cS))[lane];
    float fpa[4] = {fp4.x, fp4.y, fp4.z, fp4.w};
    float ipa[4] = {ip4.x, ip4.y, ip4.z, ip4.w};
    float p[4];
    {
        float run = 0.f;
#pragma unroll
        for (int i = 0; i < 4; ++i) {
            float xx = fpa[i];
            float lsg = fminf(xx, 0.f) - log1pf(expf(-fabsf(xx)));
            run += lsg; p[i] = run;
        }
    }
    float cum = p[3];
#pragma unroll
    for (int off = 1; off < 64; off <<= 1) { float t = __shfl_up(cum, off); if (lane >= off) cum += t; }
    float excl = cum - p[3];
    float aa[4];
#pragma unroll
    for (int i = 0; i < 4; ++i) {
        float fcv = excl + p[i];
        aa[i] = ipa[i] - fcv;
        sFc[lane * 4 + i] = fcv;
        sEA[lane * 4 + i] = __expf(aa[i]);    // exp(a[t])
    }
    float mq[4]; mq[0] = aa[0];
#pragma unroll
    for (int i = 1; i < 4; ++i) mq[i] = fmaxf(mq[i - 1], aa[i]);
    float cm = mq[3];
#pragma unroll
    for (int off = 1; off < 64; off <<= 1) { float t = __shfl_up(cm, off); if (lane >= off) cm = fmaxf(cm, t); }
    float exm = __shfl_up(cm, 1);
    if (lane == 0) exm = -3.0e38f;
#pragma unroll
    for (int i = 0; i < 4; ++i) sMx[lane * 4 + i] = fmaxf(exm, mq[i]);

    // --- stage K,V to LDS (256 threads, 1 row each) ---
    {
        int t = tid;
        const float4* kp = (const float4*)(kg + ((size_t)(b * cS) + t) * cI + h * cMDH);
        const float4* vp = (const float4*)(vg + ((size_t)(b * cS) + t) * cI + h * cMDH);
        float4* kd = (float4*)(sKf + t * cMDH);
        float4* vd = (float4*)(sVf + t * cMDH);
#pragma unroll
        for (int j = 0; j < 4; ++j) { kd[j] = kp[j]; vd[j] = vp[j]; }
    }
    float qreg[4][16];
#pragma unroll
    for (int r = 0; r < 4; ++r) {
        int s = lane + 64 * r;
        const float4* qp = (const float4*)(qg + ((size_t)(b * cS) + s) * cI + h * cMDH);
#pragma unroll
        for (int j = 0; j < 4; ++j) {
            float4 t4 = qp[j];
            qreg[r][4 * j] = t4.x; qreg[r][4 * j + 1] = t4.y; qreg[r][4 * j + 2] = t4.z; qreg[r][4 * j + 3] = t4.w;
        }
    }
    __syncthreads();

    float flr[4];
#pragma unroll
    for (int r = 0; r < 4; ++r) {
        int s = lane + 64 * r;
        float Mx = sMx[s];
        flr[r] = __expf(-(sFc[s] + Mx));
        float sc = 0.25f * __expf(-Mx);       // fold 0.25*exp(-Mx) into q
#pragma unroll
        for (int d = 0; d < 16; ++d) qreg[r][d] *= sc;
    }
    float acc[4][16];
#pragma unroll
    for (int r = 0; r < 4; ++r)
#pragma unroll
        for (int d = 0; d < 16; ++d) acc[r][d] = 0.f;
    float sumC[4] = {0, 0, 0, 0};

    for (int ch = wid; ch < 8; ch += 4) {     // 4-way interleaved chunks
        int t0 = ch * 32;
#pragma unroll 2
        for (int t = t0; t < t0 + 32; ++t) {
            float ea = sEA[t];
            float kv[16], vv[16];
#pragma unroll
            for (int j = 0; j < 4; ++j) {
                float4 t4 = ((const float4*)(sKf + t * cMDH))[j];
                kv[4 * j] = t4.x; kv[4 * j + 1] = t4.y; kv[4 * j + 2] = t4.z; kv[4 * j + 3] = t4.w;
                float4 u4 = ((const float4*)(sVf + t * cMDH))[j];
                vv[4 * j] = u4.x; vv[4 * j + 1] = u4.y; vv[4 * j + 2] = u4.z; vv[4 * j + 3] = u4.w;
            }
#pragma unroll
            for (int r = 0; r < 4; ++r) {
                if (t0 <= 63 + 64 * r) {
                    if (t <= lane + 64 * r) {
                        float d0 = fmaf(qreg[r][0], kv[0], fmaf(qreg[r][1], kv[1], fmaf(qreg[r][2], kv[2], qreg[r][3] * kv[3])));
                        float d1 = fmaf(qreg[r][4], kv[4], fmaf(qreg[r][5], kv[5], fmaf(qreg[r][6], kv[6], qreg[r][7] * kv[7])));
                        float d2 = fmaf(qreg[r][8], kv[8], fmaf(qreg[r][9], kv[9], fmaf(qreg[r][10], kv[10], qreg[r][11] * kv[11])));
                        float d3 = fmaf(qreg[r][12], kv[12], fmaf(qreg[r][13], kv[13], fmaf(qreg[r][14], kv[14], qreg[r][15] * kv[15])));
                        float ccf = ((d0 + d1) + (d2 + d3)) * ea;
                        sumC[r] += ccf;
#pragma unroll
                        for (int d = 0; d < 16; ++d) acc[r][d] += ccf * vv[d];
                    }
                }
            }
        }
    }

    // --- 4-wave reduction via dead LDS buffers ---
    __syncthreads();
    if (wid >= 2) {
        float* accDst = (wid == 2) ? sKf : sVf;
        float* sumDst = (wid == 2) ? sEA : sFc;
#pragma unroll
        for (int r = 0; r < 4; ++r) {
            float4* dst = (float4*)accDst + ((size_t)(r * 64 + lane)) * 4;
#pragma unroll
            for (int j = 0; j < 4; ++j)
                dst[j] = make_float4(acc[r][4 * j], acc[r][4 * j + 1], acc[r][4 * j + 2], acc[r][4 * j + 3]);
            sumDst[r * 64 + lane] = sumC[r];
        }
    }
    __syncthreads();
    if (wid < 2) {
        const float* accSrc = (wid == 0) ? sKf : sVf;
        const float* sumSrc = (wid == 0) ? sEA : sFc;
#pragma unroll
        for (int r = 0; r < 4; ++r) {
            const float4* src = (const float4*)accSrc + ((size_t)(r * 64 + lane)) * 4;
#pragma unroll
            for (int j = 0; j < 4; ++j) {
                float4 v = src[j];
                acc[r][4 * j] += v.x; acc[r][4 * j + 1] += v.y; acc[r][4 * j + 2] += v.z; acc[r][4 * j + 3] += v.w;
            }
            sumC[r] += sumSrc[r * 64 + lane];
        }
    }
    __syncthreads();
    if (wid == 1) {
#pragma unroll
        for (int r = 0; r < 4; ++r) {
            float4* dst = (float4*)sKf + ((size_t)(r * 64 + lane)) * 4;
#pragma unroll
            for (int j = 0; j < 4; ++j)
                dst[j] = make_float4(acc[r][4 * j], acc[r][4 * j + 1], acc[r][4 * j + 2], acc[r][4 * j + 3]);
            sEA[r * 64 + lane] = sumC[r];
        }
    }
    __syncthreads();
    if (wid == 0) {
#pragma unroll
        for (int r = 0; r < 4; ++r) {
            int s = lane + 64 * r;
            const float4* pa = (const float4*)sKf + ((size_t)(r * 64 + lane)) * 4;
            float sC = sumC[r] + sEA[r * 64 + lane];
            float nrm = fmaxf(fabsf(sC), flr[r]) + 1e-6f;
            float inv = 1.f / nrm;
            float4* op = (float4*)(hatt + ((size_t)(b * cS) + s) * cI + h * cMDH);
#pragma unroll
            for (int j = 0; j < 4; ++j) {
                float4 w1 = pa[j];
                op[j] = make_float4((acc[r][4 * j] + w1.x) * inv, (acc[r][4 * j + 1] + w1.y) * inv,
                                    (acc[r][4 * j + 2] + w1.z) * inv, (acc[r][4 * j + 3] + w1.w) * inv);
            }
        }
    }
}

// ---------------- multihead-norm + skip*x_c, gated by silu(z); in-place on hatt ----------------
__global__ __launch_bounds__(256) void mhn_y_k(float* __restrict__ hatt, const float* __restrict__ xc,
                                               const float* __restrict__ xmz, const float* __restrict__ mhnw,
                                               const float* __restrict__ skip) {
    int idx = blockIdx.x * 256 + threadIdx.x;   // B*S*NH
    int h = idx & 7; int row = idx >> 3;
    float* hp = hatt + (size_t)row * cI + h * cMDH;
    float xv[16];
#pragma unroll
    for (int d = 0; d < 16; ++d) xv[d] = hp[d];
    float mu = 0;
#pragma unroll
    for (int d = 0; d < 16; ++d) mu += xv[d];
    mu *= (1.f / 16);
    float va = 0;
#pragma unroll
    for (int d = 0; d < 16; ++d) { float dd = xv[d] - mu; va += dd * dd; }
    va *= (1.f / 16);
    float rs = rsqrtf(va + 1e-5f);
#pragma unroll
    for (int d = 0; d < 16; ++d) {
        int i = h * cMDH + d;
        float z = xmz[(size_t)row * 256 + 128 + i];
        float sg = 1.f / (1.f + __expf(-z));
        hp[d] = ((xv[d] - mu) * rs * mhnw[i] + skip[i] * xc[(size_t)row * cI + i]) * (z * sg);
    }
}

// ---------------- down-projection (128 -> 40) + residual into h ----------------
__global__ __launch_bounds__(320) void down_res_k(const float* __restrict__ y, const float* __restrict__ dw,
                                                  float* __restrict__ h) {
    __shared__ float yl[8 * 128];
    int row0 = blockIdx.x * 8;
    for (int i = threadIdx.x; i < 1024; i += 320) yl[i] = y[(size_t)row0 * cI + i];
    __syncthreads();
    int r = threadIdx.x / 40, e = threadIdx.x % 40;
    const float* dr = dw + e * cI;
    const float* yr = yl + r * cI;
    float acc = 0.f;
    for (int i = 0; i < cI; ++i) acc += yr[i] * dr[i];
    h[(size_t)(row0 + r) * cE + e] += acc;
}

// ---------------- plain row LayerNorm (E=40) ----------------
__global__ __launch_bounds__(256) void ln_rows_k(const float* __restrict__ h, const float* __restrict__ w,
                                                 float* __restrict__ out) {
    int rid = blockIdx.x * 256 + threadIdx.x;
    const float* r = h + (size_t)rid * cE;
    float mu = 0;
    for (int k = 0; k < cE; ++k) mu += r[k];
    mu *= (1.f / cE);
    float va = 0;
    for (int k = 0; k < cE; ++k) { float d = r[k] - mu; va += d * d; }
    va *= (1.f / cE);
    float rs = rsqrtf(va + 1e-5f);
    float* o = out + (size_t)rid * cE;
    for (int k = 0; k < cE; ++k) o[k] = (r[k] - mu) * rs * w[k];
}

// ---------------- sLSTM gate pre-activations; gall layout (S, B*NH, E=5, G=4) ----------------
__global__ __launch_bounds__(256) void sgates_k(const float* __restrict__ xcs, const float* __restrict__ ln1,
                                                const float* __restrict__ wi, const float* __restrict__ wf,
                                                const float* __restrict__ wz, const float* __restrict__ wo,
                                                float* __restrict__ gall) {
    int idx = blockIdx.x * 256 + threadIdx.x;   // S*1024*5*4
    int g = idx & 3; int r1 = idx >> 2;
    int e = r1 % 5; int r2 = r1 / 5;
    int bh = r2 & 1023; int s = r2 >> 10;
    int b = bh >> 3, h = bh & 7;
    const float* in = (g < 2) ? xcs : ln1;
    const float* w = (g == 0) ? wi : (g == 1) ? wf : (g == 2) ? wz : wo;
    const float* ir = in + ((size_t)(b * cS) + s) * cE + h * cDH;
    const float* wp = w + h * 25 + e * 5;
    float acc = 0.f;
#pragma unroll
    for (int i = 0; i < 5; ++i) acc += ir[i] * wp[i];
    gall[idx] = acc;
}

// ---------------- sLSTM sequential scan: 8 chains per wave (8-lane groups) ----------------
// (R6 version — measured 94.5us; R7's 2-chain interleave regressed, reverted)
__global__ __launch_bounds__(64) void scan_k(const float* __restrict__ gall, const float* __restrict__ R,
                                             const float* __restrict__ bias, const float* __restrict__ mhnw,
                                             float* __restrict__ hbuf) {
    int lane = threadIdx.x;
    int grp = lane >> 3;                 // chain within wave, 0..7
    int e = lane & 7;                    // 0..4 active, 5..7 clone e=4
    int ee = e < 5 ? e : 4;
    int bh = blockIdx.x * 8 + grp;       // 128 blocks * 8 = 1024 chains
    int h = bh & 7;

    __shared__ float sOut[8][1285];      // stride 1285 (== 5 mod 32): groups hit different banks

    float Rr[4][5];                      // R[h][g][d][ee]
#pragma unroll
    for (int g = 0; g < 4; ++g)
#pragma unroll
        for (int d = 0; d < 5; ++d) Rr[g][d] = R[h * 100 + g * 25 + d * 5 + ee];
    float bg[4];
#pragma unroll
    for (int g = 0; g < 4; ++g) bg[g] = bias[h * 20 + g * 5 + ee];
    float wmh = mhnw[h * 5 + ee];

    const float4* gp = (const float4*)gall + ((size_t)bh * 5 + ee);

    float4 rg[8];
#pragma unroll
    for (int j = 0; j < 8; ++j) rg[j] = gp[(size_t)j * 5120];

    float cstate = 0.f, nstate = 0.f, mstate = 0.f;
    float hs0 = 0.f, hs1 = 0.f, hs2 = 0.f, hs3 = 0.f, hs4 = 0.f;

    for (int t = 0; t < cS; t += 8) {
#pragma unroll
        for (int j = 0; j < 8; ++j) {
            float4 g4 = rg[j];
            rg[j] = gp[(size_t)(t + j + 8) * 5120];   // overread past t=255 lands in ws slack

            float ir = g4.x + bg[0], fr = g4.y + bg[1], zr = g4.z + bg[2], orr = g4.w + bg[3];
            ir = fmaf(hs0, Rr[0][0], ir); fr = fmaf(hs0, Rr[1][0], fr);
            zr = fmaf(hs0, Rr[2][0], zr); orr = fmaf(hs0, Rr[3][0], orr);
            ir = fmaf(hs1, Rr[0][1], ir); fr = fmaf(hs1, Rr[1][1], fr);
            zr = fmaf(hs1, Rr[2][1], zr); orr = fmaf(hs1, Rr[3][1], orr);
            ir = fmaf(hs2, Rr[0][2], ir); fr = fmaf(hs2, Rr[1][2], fr);
            zr = fmaf(hs2, Rr[2][2], zr); orr = fmaf(hs2, Rr[3][2], orr);
            ir = fmaf(hs3, Rr[0][3], ir); fr = fmaf(hs3, Rr[1][3], fr);
            zr = fmaf(hs3, Rr[2][3], zr); orr = fmaf(hs3, Rr[3][3], orr);
            ir = fmaf(hs4, Rr[0][4], ir); fr = fmaf(hs4, Rr[1][4], fr);
            zr = fmaf(hs4, Rr[2][4], zr); orr = fmaf(hs4, Rr[3][4], orr);

            float lsg = fminf(fr, 0.f) - __logf(1.f + __expf(-fabsf(fr)));
            float lfm = mstate + lsg;
            float mn = fmaxf(ir, lfm);
            float ig = __expf(ir - mn), fg = __expf(lfm - mn);
            float th = 1.f - 2.f * __builtin_amdgcn_rcpf(__expf(2.f * zr) + 1.f);
            float cn = fg * cstate + ig * th;
            float nn = fg * nstate + ig;
            float sg = __builtin_amdgcn_rcpf(1.f + __expf(-orr));
            float hn = sg * cn * __builtin_amdgcn_rcpf(nn);
            cstate = cn; nstate = nn; mstate = mn;

            hs0 = BC8(hn, 0); hs1 = BC8(hn, 1); hs2 = BC8(hn, 2);
            hs3 = BC8(hn, 3); hs4 = BC8(hn, 4);
            float mu = ((hs0 + hs1) + (hs2 + hs3) + hs4) * 0.2f;
            float d0 = hs0 - mu, d1 = hs1 - mu, d2 = hs2 - mu, d3 = hs3 - mu, d4 = hs4 - mu;
            float va = (d0 * d0 + d1 * d1 + d2 * d2 + d3 * d3 + d4 * d4) * 0.2f;
            float rs = __builtin_amdgcn_rsqf(va + 1e-5f);
            if (e < 5) sOut[grp][(t + j) * 5 + e] = (hn - mu) * rs * wmh;
        }
    }
    __syncthreads();

    for (int i = lane; i < 8 * 1280; i += 64) {
        int c = i / 1280;
        int r = i - c * 1280;
        int tt = r / 5, e2 = r - tt * 5;
        int bh2 = blockIdx.x * 8 + c;
        int b2 = bh2 >> 3, h2 = bh2 & 7;
        float* hp = hbuf + ((size_t)b2 * cS + tt) * cE + h2 * cDH + e2;
        *hp += sOut[c][r];
    }
}

// ---------------- FFN: fused LN + up-proj + exact GELU gate ----------------
__global__ __launch_bounds__(256) void ff1_k(const float* __restrict__ h, const float* __restrict__ lnw,
                                             const float* __restrict__ upw, float* __restrict__ ff) {
    __shared__ float lnr[4][cE];
    int row0 = blockIdx.x * 4;
    int tid = threadIdx.x;
    if (tid < 4) {
        const float* r = h + (size_t)(row0 + tid) * cE;
        float mu = 0;
        for (int k = 0; k < cE; ++k) mu += r[k];
        mu *= (1.f / cE);
        float va = 0;
        for (int k = 0; k < cE; ++k) { float d = r[k] - mu; va += d * d; }
        va *= (1.f / cE);
        float rs = rsqrtf(va + 1e-5f);
        for (int k = 0; k < cE; ++k) lnr[tid][k] = (r[k] - mu) * rs * lnw[k];
    }
    __syncthreads();
    int r = tid >> 6, f = tid & 63;
    float a = 0, u = 0;
    for (int k = 0; k < cE; ++k) {
        float xv = lnr[r][k];
        a += xv * upw[f * cE + k];
        u += xv * upw[(64 + f) * cE + k];
    }
    float g = 0.5f * a * (1.f + erff(a * 0.70710678118f));
    ff[(size_t)(row0 + r) * 64 + f] = g * u;
}

__global__ __launch_bounds__(320) void ff2_k(const float* __restrict__ ff, const float* __restrict__ dw,
                                             float* __restrict__ h) {
    __shared__ float fl[8 * 64];
    int row0 = blockIdx.x * 8;
    for (int i = threadIdx.x; i < 512; i += 320) fl[i] = ff[(size_t)row0 * 64 + i];
    __syncthreads();
    int r = threadIdx.x / 40, e = threadIdx.x % 40;
    const float* dr = dw + e * 64;
    const float* fr = fl + r * 64;
    float acc = 0.f;
    for (int i = 0; i < 64; ++i) acc += fr[i] * dr[i];
    h[(size_t)(row0 + r) * cE + e] += acc;
}

// ---------------- final LN + out projection ----------------
__global__ __launch_bounds__(256) void final_k(const float* __restrict__ h, const float* __restrict__ lnw,
                                               const float* __restrict__ ow, const float* __restrict__ ob,
                                               float* __restrict__ out) {
    int rid = blockIdx.x * 256 + threadIdx.x;
    const float* r = h + (size_t)rid * cE;
    float mu = 0;
    for (int k = 0; k < cE; ++k) mu += r[k];
    mu *= (1.f / cE);
    float va = 0;
    for (int k = 0; k < cE; ++k) { float d = r[k] - mu; va += d * d; }
    va *= (1.f / cE);
    float rs = rsqrtf(va + 1e-5f);
    float acc = ob[0];
    for (int k = 0; k < cE; ++k) acc += (r[k] - mu) * rs * lnw[k] * ow[k];
    out[rid] = acc;
}

extern "C" void kernel_launch(void* const* d_in, const int* in_sizes, int n_in,
                              void* d_out, int out_size, void* d_ws, size_t ws_size,
                              hipStream_t stream) {
    const float* x        = (const float*)d_in[0];
    const float* in_w     = (const float*)d_in[1];
    const float* in_b     = (const float*)d_in[2];
    const float* m_ln_w   = (const float*)d_in[3];
    const float* m_up_w   = (const float*)d_in[4];
    const float* m_conv_w = (const float*)d_in[5];
    const float* m_conv_b = (const float*)d_in[6];
    const float* m_q_w    = (const float*)d_in[7];
    const float* m_k_w    = (const float*)d_in[8];
    const float* m_v_w    = (const float*)d_in[9];
    const float* m_ig_w   = (const float*)d_in[10];
    const float* m_ig_b   = (const float*)d_in[11];
    const float* m_fg_w   = (const float*)d_in[12];
    const float* m_fg_b   = (const float*)d_in[13];
    const float* m_mhn_w  = (const float*)d_in[14];
    const float* m_skip   = (const float*)d_in[15];
    const float* m_down_w = (const float*)d_in[16];
    const float* s_ln1_w  = (const float*)d_in[17];
    const float* s_conv_w = (const float*)d_in[18];
    const float* s_conv_b = (const float*)d_in[19];
    const float* s_wi     = (const float*)d_in[20];
    const float* s_wf     = (const float*)d_in[21];
    const float* s_wz     = (const float*)d_in[22];
    const float* s_wo     = (const float*)d_in[23];
    const float* s_R      = (const float*)d_in[24];
    const float* s_bias   = (const float*)d_in[25];
    const float* s_mhn_w  = (const float*)d_in[26];
    const float* s_ln2_w  = (const float*)d_in[27];
    const float* s_ff_up  = (const float*)d_in[28];
    const float* s_ff_dn  = (const float*)d_in[29];
    const float* post_ln_w= (const float*)d_in[30];
    const float* out_w    = (const float*)d_in[31];
    const float* out_b    = (const float*)d_in[32];

    float* ws   = (float*)d_ws;
    float* h    = ws;                     // 1,310,720
    float* xmz  = h + 1310720;            // 8,388,608
    float* xc   = xmz + 8388608;          // 4,194,304
    float* qb   = xc + 4194304;           // 4,194,304
    float* kb   = qb + 4194304;           // 4,194,304
    float* vb   = kb + 4194304;           // 4,194,304
    float* ipb  = vb + 4194304;           //   262,144
    float* fpb  = ipb + 262144;           //   262,144
    float* hatt = fpb + 262144;           // 4,194,304   (~119 MB total)
    // slstm / ff aliases into the xmz region (dead at those points)
    float* lnbuf = xmz;                   // 1,310,720
    float* xcs   = xmz + 1310720;         // 1,310,720
    float* gall  = xmz + 2621440;         // 5,242,880 (+ scan overreads into tail slack)
    float* ffbuf = xmz;                   // 2,097,152

    init_k<<<5120, 256, 0, stream>>>(x, in_w, in_b, h);

    auto mlstm = [&](int j) {
        ln_up_k<<<4096, 256, 0, stream>>>(h, m_ln_w + j * cE, m_up_w + (size_t)j * 256 * cE, xmz);
        conv_silu_k<128><<<16384, 256, 0, stream>>>(xmz, 256, m_conv_w + j * cI * cK, m_conv_b + j * cI, xc);
        qkv_k<<<16384, 256, 0, stream>>>(xc, xmz, m_q_w + j * 512, m_k_w + j * 512, m_v_w + j * 512, qb, kb, vb);
        gates_k<<<1024, 128, 0, stream>>>(qb, kb, vb, m_ig_w + j * cNH * 384, m_ig_b + j * cNH,
                                          m_fg_w + j * cNH * 384, m_fg_b + j * cNH, ipb, fpb);
        attn_k<<<1024, 256, 0, stream>>>(qb, kb, vb, ipb, fpb, hatt);
        mhn_y_k<<<1024, 256, 0, stream>>>(hatt, xc, xmz, m_mhn_w + j * cI, m_skip + j * cI);
        down_res_k<<<4096, 320, 0, stream>>>(hatt, m_down_w + j * cE * cI, h);
    };

    mlstm(0);

    ln_rows_k<<<128, 256, 0, stream>>>(h, s_ln1_w, lnbuf);
    conv_silu_k<40><<<5120, 256, 0, stream>>>(lnbuf, 40, s_conv_w, s_conv_b, xcs);
    sgates_k<<<20480, 256, 0, stream>>>(xcs, lnbuf, s_wi, s_wf, s_wz, s_wo, gall);
    scan_k<<<128, 64, 0, stream>>>(gall, s_R, s_bias, s_mhn_w, h);

    ff1_k<<<8192, 256, 0, stream>>>(h, s_ln2_w, s_ff_up, ffbuf);
    ff2_k<<<4096, 320, 0, stream>>>(ffbuf, s_ff_dn, h);

    mlstm(1);
    mlstm(2);

    final_k<<<128, 256, 0, stream>>>(h, post_ln_w, out_w, out_b, (float*)d_out);
}

// Round 10
// 1015.173 us; speedup vs baseline: 1.0974x; 1.0974x over previous
//
#include <hip/hip_runtime.h>
#include <math.h>

constexpr int cB = 128, cS = 256, cF = 10, cE = 40, cNH = 8, cDH = 5;
constexpr int cI = 128, cMDH = 16, cK = 4;

// broadcast lane (group_base + l) to all 8 lanes of the group (groups of 8 within 32-lane halves)
#define BC8(v, l) __uint_as_float(__builtin_amdgcn_ds_swizzle(__float_as_uint(v), ((l) << 5) | 0x18))

// ---------------- h = x @ in_w.T + in_b + pos_encoding ----------------
__global__ __launch_bounds__(256) void init_k(const float* __restrict__ x, const float* __restrict__ w,
                                              const float* __restrict__ b, float* __restrict__ h) {
    int idx = blockIdx.x * 256 + threadIdx.x;     // B*S*E
    int e = idx % cE; int bs = idx / cE; int s = bs % cS;
    float acc = b[e];
    const float* xr = x + (size_t)bs * cF;
#pragma unroll
    for (int f = 0; f < cF; ++f) acc += xr[f] * w[e * cF + f];
    int i2 = e >> 1;
    float div = expf(-(float)(2 * i2) * (logf(10000.f) / 40.0f));
    float arg = (float)s * div;
    acc += (e & 1) ? cosf(arg) : sinf(arg);
    h[idx] = acc;
}

// ---------------- fused LayerNorm + up-projection (E=40 -> 256) ----------------
__global__ __launch_bounds__(256) void ln_up_k(const float* __restrict__ h, const float* __restrict__ lnw,
                                               const float* __restrict__ upw, float* __restrict__ xmz) {
    __shared__ float lnr[8][cE];
    int row0 = blockIdx.x * 8;
    int tid = threadIdx.x;
    if (tid < 8) {
        const float* r = h + (size_t)(row0 + tid) * cE;
        float mu = 0.f;
        for (int k = 0; k < cE; ++k) mu += r[k];
        mu *= (1.f / cE);
        float va = 0.f;
        for (int k = 0; k < cE; ++k) { float d = r[k] - mu; va += d * d; }
        va *= (1.f / cE);
        float rs = rsqrtf(va + 1e-5f);
        for (int k = 0; k < cE; ++k) lnr[tid][k] = (r[k] - mu) * rs * lnw[k];
    }
    __syncthreads();
    int o = tid;   // 0..255
    float acc[8] = {0, 0, 0, 0, 0, 0, 0, 0};
    for (int k = 0; k < cE; ++k) {
        float wv = upw[o * cE + k];
#pragma unroll
        for (int r = 0; r < 8; ++r) acc[r] += lnr[r][k] * wv;
    }
#pragma unroll
    for (int r = 0; r < 8; ++r) xmz[(size_t)(row0 + r) * 256 + o] = acc[r];
}

// ---------------- depthwise causal conv (K=4) + SiLU ----------------
template <int C>
__global__ __launch_bounds__(256) void conv_silu_k(const float* __restrict__ in, int instride,
                                                   const float* __restrict__ w, const float* __restrict__ bias,
                                                   float* __restrict__ out) {
    int idx = blockIdx.x * 256 + threadIdx.x;   // B*S*C
    int c = idx % C; int bs = idx / C; int s = bs % cS;
    float acc = bias[c];
#pragma unroll
    for (int j = 0; j < cK; ++j) {
        int sj = s - 3 + j;
        if (sj >= 0) acc += in[(size_t)(bs + j - 3) * instride + c] * w[c * cK + j];
    }
    float sg = 1.f / (1.f + __expf(-acc));
    out[idx] = acc * sg;
}

// ---------------- block-diagonal headwise q,k,v ----------------
__global__ __launch_bounds__(256) void qkv_k(const float* __restrict__ xc, const float* __restrict__ xmz,
                                             const float* __restrict__ qw, const float* __restrict__ kw,
                                             const float* __restrict__ vw,
                                             float* __restrict__ qb, float* __restrict__ kb, float* __restrict__ vb) {
    int idx = blockIdx.x * 256 + threadIdx.x;   // B*S*I
    int c = idx & 127; int bs = idx >> 7;
    int n = c >> 2, o = c & 3;
    const float* xcr = xc + (size_t)bs * cI + n * 4;
    const float* xmr = xmz + (size_t)bs * 256 + n * 4;
    const float* qwp = qw + n * 16 + o * 4;
    const float* kwp = kw + n * 16 + o * 4;
    const float* vwp = vw + n * 16 + o * 4;
    float aq = 0, ak = 0, av = 0;
#pragma unroll
    for (int i = 0; i < 4; ++i) { float a = xcr[i], m = xmr[i]; aq += a * qwp[i]; ak += a * kwp[i]; av += m * vwp[i]; }
    qb[idx] = aq; kb[idx] = ak; vb[idx] = av;
}

// ---------------- input/forget gate pre-activations ip, fp (B,NH,S) v2 ----------------
__global__ __launch_bounds__(128, 2) void gates_k(const float* __restrict__ qb, const float* __restrict__ kb,
                                                  const float* __restrict__ vb, const float* __restrict__ igw,
                                                  const float* __restrict__ igb, const float* __restrict__ fgw,
                                                  const float* __restrict__ fgb,
                                                  float* __restrict__ ipb, float* __restrict__ fpb) {
    __shared__ float g[32 * 388];
    __shared__ float w[16 * 388];
    int row0 = blockIdx.x * 32;
    int tid = threadIdx.x;

    for (int i = tid; i < 16 * 96; i += 128) {
        int r = i / 96, c4 = i - r * 96;
        const float* src = (r < 8) ? (igw + r * 384) : (fgw + (r - 8) * 384);
        *(float4*)&w[r * 388 + c4 * 4] = ((const float4*)src)[c4];
    }
    for (int i = tid; i < 32 * 96; i += 128) {
        int r = i / 96, c4 = i - r * 96;
        size_t gr = (size_t)(row0 + r) * cI;
        const float4* src = (c4 < 32) ? (const float4*)(qb + gr) + c4
                          : (c4 < 64) ? (const float4*)(kb + gr) + (c4 - 32)
                                      : (const float4*)(vb + gr) + (c4 - 64);
        *(float4*)&g[r * 388 + c4 * 4] = *src;
    }
    __syncthreads();

    int rp = tid >> 3;
    int hp = tid & 7;
    int r0 = 2 * rp, r1 = r0 + 1;
    int o0 = 2 * hp, o1 = o0 + 1;

    const float4* g0p = (const float4*)(g + r0 * 388);
    const float4* g1p = (const float4*)(g + r1 * 388);
    const float4* w0p = (const float4*)(w + o0 * 388);
    const float4* w1p = (const float4*)(w + o1 * 388);

    float a00 = 0.f, a01 = 0.f, a10 = 0.f, a11 = 0.f;
#pragma unroll 4
    for (int c4 = 0; c4 < 96; ++c4) {
        float4 gv0 = g0p[c4], gv1 = g1p[c4];
        float4 wv0 = w0p[c4], wv1 = w1p[c4];
        a00 = fmaf(gv0.x, wv0.x, a00); a00 = fmaf(gv0.y, wv0.y, a00);
        a00 = fmaf(gv0.z, wv0.z, a00); a00 = fmaf(gv0.w, wv0.w, a00);
        a01 = fmaf(gv0.x, wv1.x, a01); a01 = fmaf(gv0.y, wv1.y, a01);
        a01 = fmaf(gv0.z, wv1.z, a01); a01 = fmaf(gv0.w, wv1.w, a01);
        a10 = fmaf(gv1.x, wv0.x, a10); a10 = fmaf(gv1.y, wv0.y, a10);
        a10 = fmaf(gv1.z, wv0.z, a10); a10 = fmaf(gv1.w, wv0.w, a10);
        a11 = fmaf(gv1.x, wv1.x, a11); a11 = fmaf(gv1.y, wv1.y, a11);
        a11 = fmaf(gv1.z, wv1.z, a11); a11 = fmaf(gv1.w, wv1.w, a11);
    }

    int h0 = o0 & 7, wch0 = o0 >> 3;
    int h1 = o1 & 7, wch1 = o1 >> 3;
    float b0 = wch0 ? fgb[h0] : igb[h0];
    float b1 = wch1 ? fgb[h1] : igb[h1];
    int grow0 = row0 + r0, grow1 = row0 + r1;
    int bb0 = grow0 >> 8, ss0 = grow0 & 255;
    int bb1 = grow1 >> 8, ss1 = grow1 & 255;
    float* d00 = (wch0 ? fpb : ipb) + (size_t)(bb0 * cNH + h0) * cS + ss0;
    float* d01 = (wch1 ? fpb : ipb) + (size_t)(bb0 * cNH + h1) * cS + ss0;
    float* d10 = (wch0 ? fpb : ipb) + (size_t)(bb1 * cNH + h0) * cS + ss1;
    float* d11 = (wch1 ? fpb : ipb) + (size_t)(bb1 * cNH + h1) * cS + ss1;
    *d00 = a00 + b0; *d01 = a01 + b1; *d10 = a10 + b0; *d11 = a11 + b1;
}

// ---------------- fused mLSTM attention (v4, reverted): 2 waves per (b,h) ----------------
// Known-good ~90us. Interleaved 32-t-chunks; K/V staged once in LDS; 4 rows/lane.
__global__ __launch_bounds__(128, 2) void attn_k(const float* __restrict__ qg, const float* __restrict__ kg,
                                                 const float* __restrict__ vg, const float* __restrict__ ipg,
                                                 const float* __restrict__ fpg, float* __restrict__ hatt) {
    int bh = blockIdx.x; int b = bh >> 3, h = bh & 7;
    int tid = threadIdx.x;
    int wid = tid >> 6, lane = tid & 63;
    __shared__ float sEA[cS], sMx[cS], sFc[cS];
    __shared__ float sKf[cS * cMDH], sVf[cS * cMDH];

    const float4 fp4 = ((const float4*)(fpg + (size_t)bh * cS))[lane];
    const float4 ip4 = ((const float4*)(ipg + (size_t)bh * cS))[lane];
    float fpa[4] = {fp4.x, fp4.y, fp4.z, fp4.w};
    float ipa[4] = {ip4.x, ip4.y, ip4.z, ip4.w};
    float p[4];
    {
        float run = 0.f;
#pragma unroll
        for (int i = 0; i < 4; ++i) {
            float xx = fpa[i];
            float lsg = fminf(xx, 0.f) - log1pf(expf(-fabsf(xx)));
            run += lsg; p[i] = run;
        }
    }
    float cum = p[3];
#pragma unroll
    for (int off = 1; off < 64; off <<= 1) { float t = __shfl_up(cum, off); if (lane >= off) cum += t; }
    float excl = cum - p[3];
    float aa[4];
#pragma unroll
    for (int i = 0; i < 4; ++i) {
        float fcv = excl + p[i];
        aa[i] = ipa[i] - fcv;
        sFc[lane * 4 + i] = fcv;
        sEA[lane * 4 + i] = __expf(aa[i]);    // exp(a[t])
    }
    float mq[4]; mq[0] = aa[0];
#pragma unroll
    for (int i = 1; i < 4; ++i) mq[i] = fmaxf(mq[i - 1], aa[i]);
    float cm = mq[3];
#pragma unroll
    for (int off = 1; off < 64; off <<= 1) { float t = __shfl_up(cm, off); if (lane >= off) cm = fmaxf(cm, t); }
    float exm = __shfl_up(cm, 1);
    if (lane == 0) exm = -3.0e38f;
#pragma unroll
    for (int i = 0; i < 4; ++i) sMx[lane * 4 + i] = fmaxf(exm, mq[i]);

#pragma unroll
    for (int rr = 0; rr < 2; ++rr) {
        int t = tid + 128 * rr;
        const float4* kp = (const float4*)(kg + ((size_t)(b * cS) + t) * cI + h * cMDH);
        const float4* vp = (const float4*)(vg + ((size_t)(b * cS) + t) * cI + h * cMDH);
        float4* kd = (float4*)(sKf + t * cMDH);
        float4* vd = (float4*)(sVf + t * cMDH);
#pragma unroll
        for (int j = 0; j < 4; ++j) { kd[j] = kp[j]; vd[j] = vp[j]; }
    }
    float qreg[4][16];
#pragma unroll
    for (int r = 0; r < 4; ++r) {
        int s = lane + 64 * r;
        const float4* qp = (const float4*)(qg + ((size_t)(b * cS) + s) * cI + h * cMDH);
#pragma unroll
        for (int j = 0; j < 4; ++j) {
            float4 t4 = qp[j];
            qreg[r][4 * j] = t4.x; qreg[r][4 * j + 1] = t4.y; qreg[r][4 * j + 2] = t4.z; qreg[r][4 * j + 3] = t4.w;
        }
    }
    __syncthreads();

    float MxR[4], flr[4], eMx[4];
#pragma unroll
    for (int r = 0; r < 4; ++r) {
        int s = lane + 64 * r;
        MxR[r] = sMx[s];
        flr[r] = __expf(-(sFc[s] + MxR[r]));
        eMx[r] = __expf(-MxR[r]);
    }
    float acc[4][16];
#pragma unroll
    for (int r = 0; r < 4; ++r)
#pragma unroll
        for (int d = 0; d < 16; ++d) acc[r][d] = 0.f;
    float sumC[4] = {0, 0, 0, 0};

    for (int ch = wid; ch < 8; ch += 2) {
        int t0 = ch * 32;
#pragma unroll 2
        for (int t = t0; t < t0 + 32; ++t) {
            float ea = sEA[t];
            float kv[16], vv[16];
#pragma unroll
            for (int j = 0; j < 4; ++j) {
                float4 t4 = ((const float4*)(sKf + t * cMDH))[j];
                kv[4 * j] = t4.x; kv[4 * j + 1] = t4.y; kv[4 * j + 2] = t4.z; kv[4 * j + 3] = t4.w;
                float4 u4 = ((const float4*)(sVf + t * cMDH))[j];
                vv[4 * j] = u4.x; vv[4 * j + 1] = u4.y; vv[4 * j + 2] = u4.z; vv[4 * j + 3] = u4.w;
            }
#pragma unroll
            for (int r = 0; r < 4; ++r) {
                if (t0 <= 63 + 64 * r) {
                    if (t <= lane + 64 * r) {
                        float wgt = ea * eMx[r];
                        float d0 = fmaf(qreg[r][0], kv[0], fmaf(qreg[r][1], kv[1], fmaf(qreg[r][2], kv[2], qreg[r][3] * kv[3])));
                        float d1 = fmaf(qreg[r][4], kv[4], fmaf(qreg[r][5], kv[5], fmaf(qreg[r][6], kv[6], qreg[r][7] * kv[7])));
                        float d2 = fmaf(qreg[r][8], kv[8], fmaf(qreg[r][9], kv[9], fmaf(qreg[r][10], kv[10], qreg[r][11] * kv[11])));
                        float d3 = fmaf(qreg[r][12], kv[12], fmaf(qreg[r][13], kv[13], fmaf(qreg[r][14], kv[14], qreg[r][15] * kv[15])));
                        float qk = (d0 + d1) + (d2 + d3);
                        float ccf = qk * 0.25f * wgt;
                        sumC[r] += ccf;
#pragma unroll
                        for (int d = 0; d < 16; ++d) acc[r][d] += ccf * vv[d];
                    }
                }
            }
        }
    }

    __syncthreads();
    if (wid == 1) {
#pragma unroll
        for (int r = 0; r < 4; ++r) {
            float4* dst = (float4*)sKf + ((size_t)(r * 64 + lane)) * 4;
#pragma unroll
            for (int j = 0; j < 4; ++j)
                dst[j] = make_float4(acc[r][4 * j], acc[r][4 * j + 1], acc[r][4 * j + 2], acc[r][4 * j + 3]);
            sMx[r * 64 + lane] = sumC[r];
        }
    }
    __syncthreads();
    if (wid == 0) {
#pragma unroll
        for (int r = 0; r < 4; ++r) {
            int s = lane + 64 * r;
            const float4* pa = (const float4*)sKf + ((size_t)(r * 64 + lane)) * 4;
            float sC = sumC[r] + sMx[r * 64 + lane];
            float nrm = fmaxf(fabsf(sC), flr[r]) + 1e-6f;
            float inv = 1.f / nrm;
            float4* op = (float4*)(hatt + ((size_t)(b * cS) + s) * cI + h * cMDH);
#pragma unroll
            for (int j = 0; j < 4; ++j) {
                float4 w1 = pa[j];
                op[j] = make_float4((acc[r][4 * j] + w1.x) * inv, (acc[r][4 * j + 1] + w1.y) * inv,
                                    (acc[r][4 * j + 2] + w1.z) * inv, (acc[r][4 * j + 3] + w1.w) * inv);
            }
        }
    }
}

// ---------------- fused multihead-norm + gate + down-projection + residual ----------------
// Replaces mhn_y_k + down_res_k: saves one 16.7MB hatt write + 16.7MB read + a launch.
__global__ __launch_bounds__(320) void down_mhn_k(const float* __restrict__ hatt, const float* __restrict__ xc,
                                                  const float* __restrict__ xmz, const float* __restrict__ mhnw,
                                                  const float* __restrict__ skip, const float* __restrict__ dw,
                                                  float* __restrict__ h) {
    __shared__ float yl[8 * 128];
    int row0 = blockIdx.x * 8;
    int tid = threadIdx.x;
    for (int i = tid; i < 1024; i += 320) yl[i] = hatt[(size_t)row0 * cI + i];
    __syncthreads();
    if (tid < 64) {                       // one thread per (row, head) group of 16
        int r = tid >> 3, hh = tid & 7;
        int row = row0 + r;
        float* g = yl + r * 128 + hh * 16;
        float xv[16];
        float mu = 0.f;
#pragma unroll
        for (int d = 0; d < 16; ++d) { xv[d] = g[d]; mu += xv[d]; }
        mu *= (1.f / 16);
        float va = 0.f;
#pragma unroll
        for (int d = 0; d < 16; ++d) { float dd = xv[d] - mu; va += dd * dd; }
        va *= (1.f / 16);
        float rs = rsqrtf(va + 1e-5f);
        const float* xcr = xc + (size_t)row * cI + hh * 16;
        const float* zr  = xmz + (size_t)row * 256 + 128 + hh * 16;
#pragma unroll
        for (int d = 0; d < 16; ++d) {
            int i = hh * 16 + d;
            float z = zr[d];
            float sg = 1.f / (1.f + __expf(-z));
            g[d] = ((xv[d] - mu) * rs * mhnw[i] + skip[i] * xcr[d]) * (z * sg);
        }
    }
    __syncthreads();
    int r = tid / 40, e = tid % 40;
    const float* dr = dw + e * cI;
    const float* yr = yl + r * cI;
    float acc = 0.f;
    for (int i = 0; i < cI; ++i) acc += yr[i] * dr[i];
    h[(size_t)(row0 + r) * cE + e] += acc;
}

// ---------------- plain row LayerNorm (E=40) ----------------
__global__ __launch_bounds__(256) void ln_rows_k(const float* __restrict__ h, const float* __restrict__ w,
                                                 float* __restrict__ out) {
    int rid = blockIdx.x * 256 + threadIdx.x;
    const float* r = h + (size_t)rid * cE;
    float mu = 0;
    for (int k = 0; k < cE; ++k) mu += r[k];
    mu *= (1.f / cE);
    float va = 0;
    for (int k = 0; k < cE; ++k) { float d = r[k] - mu; va += d * d; }
    va *= (1.f / cE);
    float rs = rsqrtf(va + 1e-5f);
    float* o = out + (size_t)rid * cE;
    for (int k = 0; k < cE; ++k) o[k] = (r[k] - mu) * rs * w[k];
}

// ---------------- sLSTM gate pre-activations; gall layout (S, B*NH, E=5, G=4) ----------------
__global__ __launch_bounds__(256) void sgates_k(const float* __restrict__ xcs, const float* __restrict__ ln1,
                                                const float* __restrict__ wi, const float* __restrict__ wf,
                                                const float* __restrict__ wz, const float* __restrict__ wo,
                                                float* __restrict__ gall) {
    int idx = blockIdx.x * 256 + threadIdx.x;   // S*1024*5*4
    int g = idx & 3; int r1 = idx >> 2;
    int e = r1 % 5; int r2 = r1 / 5;
    int bh = r2 & 1023; int s = r2 >> 10;
    int b = bh >> 3, h = bh & 7;
    const float* in = (g < 2) ? xcs : ln1;
    const float* w = (g == 0) ? wi : (g == 1) ? wf : (g == 2) ? wz : wo;
    const float* ir = in + ((size_t)(b * cS) + s) * cE + h * cDH;
    const float* wp = w + h * 25 + e * 5;
    float acc = 0.f;
#pragma unroll
    for (int i = 0; i < 5; ++i) acc += ir[i] * wp[i];
    gall[idx] = acc;
}

// ---------------- sLSTM sequential scan: 8 chains per wave, 16-deep prefetch ----------------
// R6 structure (94.5us) + ring depth 8->16: load issue->use distance ~2080cy now
// covers the ~900cy HBM-miss latency (gall written by other XCDs' L2s).
__global__ __launch_bounds__(64) void scan_k(const float* __restrict__ gall, const float* __restrict__ R,
                                             const float* __restrict__ bias, const float* __restrict__ mhnw,
                                             float* __restrict__ hbuf) {
    int lane = threadIdx.x;
    int grp = lane >> 3;                 // chain within wave, 0..7
    int e = lane & 7;                    // 0..4 active, 5..7 clone e=4
    int ee = e < 5 ? e : 4;
    int bh = blockIdx.x * 8 + grp;       // 128 blocks * 8 = 1024 chains
    int h = bh & 7;

    __shared__ float sOut[8][1285];      // stride 1285 (== 5 mod 32): groups hit different banks

    float Rr[4][5];                      // R[h][g][d][ee]
#pragma unroll
    for (int g = 0; g < 4; ++g)
#pragma unroll
        for (int d = 0; d < 5; ++d) Rr[g][d] = R[h * 100 + g * 25 + d * 5 + ee];
    float bg[4];
#pragma unroll
    for (int g = 0; g < 4; ++g) bg[g] = bias[h * 20 + g * 5 + ee];
    float wmh = mhnw[h * 5 + ee];

    const float4* gp = (const float4*)gall + ((size_t)bh * 5 + ee);

    float4 rg[16];
#pragma unroll
    for (int j = 0; j < 16; ++j) rg[j] = gp[(size_t)j * 5120];

    float cstate = 0.f, nstate = 0.f, mstate = 0.f;
    float hs0 = 0.f, hs1 = 0.f, hs2 = 0.f, hs3 = 0.f, hs4 = 0.f;

    for (int t = 0; t < cS; t += 16) {
#pragma unroll
        for (int j = 0; j < 16; ++j) {
            float4 g4 = rg[j];
            rg[j] = gp[(size_t)(t + j + 16) * 5120];   // overread past t=255 lands in ws slack

            float ir = g4.x + bg[0], fr = g4.y + bg[1], zr = g4.z + bg[2], orr = g4.w + bg[3];
            ir = fmaf(hs0, Rr[0][0], ir); fr = fmaf(hs0, Rr[1][0], fr);
            zr = fmaf(hs0, Rr[2][0], zr); orr = fmaf(hs0, Rr[3][0], orr);
            ir = fmaf(hs1, Rr[0][1], ir); fr = fmaf(hs1, Rr[1][1], fr);
            zr = fmaf(hs1, Rr[2][1], zr); orr = fmaf(hs1, Rr[3][1], orr);
            ir = fmaf(hs2, Rr[0][2], ir); fr = fmaf(hs2, Rr[1][2], fr);
            zr = fmaf(hs2, Rr[2][2], zr); orr = fmaf(hs2, Rr[3][2], orr);
            ir = fmaf(hs3, Rr[0][3], ir); fr = fmaf(hs3, Rr[1][3], fr);
            zr = fmaf(hs3, Rr[2][3], zr); orr = fmaf(hs3, Rr[3][3], orr);
            ir = fmaf(hs4, Rr[0][4], ir); fr = fmaf(hs4, Rr[1][4], fr);
            zr = fmaf(hs4, Rr[2][4], zr); orr = fmaf(hs4, Rr[3][4], orr);

            float lsg = fminf(fr, 0.f) - __logf(1.f + __expf(-fabsf(fr)));
            float lfm = mstate + lsg;
            float mn = fmaxf(ir, lfm);
            float ig = __expf(ir - mn), fg = __expf(lfm - mn);
            float th = 1.f - 2.f * __builtin_amdgcn_rcpf(__expf(2.f * zr) + 1.f);
            float cn = fg * cstate + ig * th;
            float nn = fg * nstate + ig;
            float sg = __builtin_amdgcn_rcpf(1.f + __expf(-orr));
            float hn = sg * cn * __builtin_amdgcn_rcpf(nn);
            cstate = cn; nstate = nn; mstate = mn;

            hs0 = BC8(hn, 0); hs1 = BC8(hn, 1); hs2 = BC8(hn, 2);
            hs3 = BC8(hn, 3); hs4 = BC8(hn, 4);
            float mu = ((hs0 + hs1) + (hs2 + hs3) + hs4) * 0.2f;
            float d0 = hs0 - mu, d1 = hs1 - mu, d2 = hs2 - mu, d3 = hs3 - mu, d4 = hs4 - mu;
            float va = (d0 * d0 + d1 * d1 + d2 * d2 + d3 * d3 + d4 * d4) * 0.2f;
            float rs = __builtin_amdgcn_rsqf(va + 1e-5f);
            if (e < 5) sOut[grp][(t + j) * 5 + e] = (hn - mu) * rs * wmh;
        }
    }
    __syncthreads();

    for (int i = lane; i < 8 * 1280; i += 64) {
        int c = i / 1280;
        int r = i - c * 1280;
        int tt = r / 5, e2 = r - tt * 5;
        int bh2 = blockIdx.x * 8 + c;
        int b2 = bh2 >> 3, h2 = bh2 & 7;
        float* hp = hbuf + ((size_t)b2 * cS + tt) * cE + h2 * cDH + e2;
        *hp += sOut[c][r];
    }
}

// ---------------- FFN: fused LN + up-proj + exact GELU gate ----------------
__global__ __launch_bounds__(256) void ff1_k(const float* __restrict__ h, const float* __restrict__ lnw,
                                             const float* __restrict__ upw, float* __restrict__ ff) {
    __shared__ float lnr[4][cE];
    int row0 = blockIdx.x * 4;
    int tid = threadIdx.x;
    if (tid < 4) {
        const float* r = h + (size_t)(row0 + tid) * cE;
        float mu = 0;
        for (int k = 0; k < cE; ++k) mu += r[k];
        mu *= (1.f / cE);
        float va = 0;
        for (int k = 0; k < cE; ++k) { float d = r[k] - mu; va += d * d; }
        va *= (1.f / cE);
        float rs = rsqrtf(va + 1e-5f);
        for (int k = 0; k < cE; ++k) lnr[tid][k] = (r[k] - mu) * rs * lnw[k];
    }
    __syncthreads();
    int r = tid >> 6, f = tid & 63;
    float a = 0, u = 0;
    for (int k = 0; k < cE; ++k) {
        float xv = lnr[r][k];
        a += xv * upw[f * cE + k];
        u += xv * upw[(64 + f) * cE + k];
    }
    float g = 0.5f * a * (1.f + erff(a * 0.70710678118f));
    ff[(size_t)(row0 + r) * 64 + f] = g * u;
}

__global__ __launch_bounds__(320) void ff2_k(const float* __restrict__ ff, const float* __restrict__ dw,
                                             float* __restrict__ h) {
    __shared__ float fl[8 * 64];
    int row0 = blockIdx.x * 8;
    for (int i = threadIdx.x; i < 512; i += 320) fl[i] = ff[(size_t)row0 * 64 + i];
    __syncthreads();
    int r = threadIdx.x / 40, e = threadIdx.x % 40;
    const float* dr = dw + e * 64;
    const float* fr = fl + r * 64;
    float acc = 0.f;
    for (int i = 0; i < 64; ++i) acc += fr[i] * dr[i];
    h[(size_t)(row0 + r) * cE + e] += acc;
}

// ---------------- final LN + out projection ----------------
__global__ __launch_bounds__(256) void final_k(const float* __restrict__ h, const float* __restrict__ lnw,
                                               const float* __restrict__ ow, const float* __restrict__ ob,
                                               float* __restrict__ out) {
    int rid = blockIdx.x * 256 + threadIdx.x;
    const float* r = h + (size_t)rid * cE;
    float mu = 0;
    for (int k = 0; k < cE; ++k) mu += r[k];
    mu *= (1.f / cE);
    float va = 0;
    for (int k = 0; k < cE; ++k) { float d = r[k] - mu; va += d * d; }
    va *= (1.f / cE);
    float rs = rsqrtf(va + 1e-5f);
    float acc = ob[0];
    for (int k = 0; k < cE; ++k) acc += (r[k] - mu) * rs * lnw[k] * ow[k];
    out[rid] = acc;
}

extern "C" void kernel_launch(void* const* d_in, const int* in_sizes, int n_in,
                              void* d_out, int out_size, void* d_ws, size_t ws_size,
                              hipStream_t stream) {
    const float* x        = (const float*)d_in[0];
    const float* in_w     = (const float*)d_in[1];
    const float* in_b     = (const float*)d_in[2];
    const float* m_ln_w   = (const float*)d_in[3];
    const float* m_up_w   = (const float*)d_in[4];
    const float* m_conv_w = (const float*)d_in[5];
    const float* m_conv_b = (const float*)d_in[6];
    const float* m_q_w    = (const float*)d_in[7];
    const float* m_k_w    = (const float*)d_in[8];
    const float* m_v_w    = (const float*)d_in[9];
    const float* m_ig_w   = (const float*)d_in[10];
    const float* m_ig_b   = (const float*)d_in[11];
    const float* m_fg_w   = (const float*)d_in[12];
    const float* m_fg_b   = (const float*)d_in[13];
    const float* m_mhn_w  = (const float*)d_in[14];
    const float* m_skip   = (const float*)d_in[15];
    const float* m_down_w = (const float*)d_in[16];
    const float* s_ln1_w  = (const float*)d_in[17];
    const float* s_conv_w = (const float*)d_in[18];
    const float* s_conv_b = (const float*)d_in[19];
    const float* s_wi     = (const float*)d_in[20];
    const float* s_wf     = (const float*)d_in[21];
    const float* s_wz     = (const float*)d_in[22];
    const float* s_wo     = (const float*)d_in[23];
    const float* s_R      = (const float*)d_in[24];
    const float* s_bias   = (const float*)d_in[25];
    const float* s_mhn_w  = (const float*)d_in[26];
    const float* s_ln2_w  = (const float*)d_in[27];
    const float* s_ff_up  = (const float*)d_in[28];
    const float* s_ff_dn  = (const float*)d_in[29];
    const float* post_ln_w= (const float*)d_in[30];
    const float* out_w    = (const float*)d_in[31];
    const float* out_b    = (const float*)d_in[32];

    float* ws   = (float*)d_ws;
    float* h    = ws;                     // 1,310,720
    float* xmz  = h + 1310720;            // 8,388,608
    float* xc   = xmz + 8388608;          // 4,194,304
    float* qb   = xc + 4194304;           // 4,194,304
    float* kb   = qb + 4194304;           // 4,194,304
    float* vb   = kb + 4194304;           // 4,194,304
    float* ipb  = vb + 4194304;           //   262,144
    float* fpb  = ipb + 262144;           //   262,144
    float* hatt = fpb + 262144;           // 4,194,304   (~119 MB total)
    // slstm / ff aliases into the xmz region (dead at those points)
    float* lnbuf = xmz;                   // 1,310,720
    float* xcs   = xmz + 1310720;         // 1,310,720
    float* gall  = xmz + 2621440;         // 5,242,880 (+ scan overreads into tail slack)
    float* ffbuf = xmz;                   // 2,097,152

    init_k<<<5120, 256, 0, stream>>>(x, in_w, in_b, h);

    auto mlstm = [&](int j) {
        ln_up_k<<<4096, 256, 0, stream>>>(h, m_ln_w + j * cE, m_up_w + (size_t)j * 256 * cE, xmz);
        conv_silu_k<128><<<16384, 256, 0, stream>>>(xmz, 256, m_conv_w + j * cI * cK, m_conv_b + j * cI, xc);
        qkv_k<<<16384, 256, 0, stream>>>(xc, xmz, m_q_w + j * 512, m_k_w + j * 512, m_v_w + j * 512, qb, kb, vb);
        gates_k<<<1024, 128, 0, stream>>>(qb, kb, vb, m_ig_w + j * cNH * 384, m_ig_b + j * cNH,
                                          m_fg_w + j * cNH * 384, m_fg_b + j * cNH, ipb, fpb);
        attn_k<<<1024, 128, 0, stream>>>(qb, kb, vb, ipb, fpb, hatt);
        down_mhn_k<<<4096, 320, 0, stream>>>(hatt, xc, xmz, m_mhn_w + j * cI, m_skip + j * cI,
                                             m_down_w + j * cE * cI, h);
    };

    mlstm(0);

    ln_rows_k<<<128, 256, 0, stream>>>(h, s_ln1_w, lnbuf);
    conv_silu_k<40><<<5120, 256, 0, stream>>>(lnbuf, 40, s_conv_w, s_conv_b, xcs);
    sgates_k<<<20480, 256, 0, stream>>>(xcs, lnbuf, s_wi, s_wf, s_wz, s_wo, gall);
    scan_k<<<128, 64, 0, stream>>>(gall, s_R, s_bias, s_mhn_w, h);

    ff1_k<<<8192, 256, 0, stream>>>(h, s_ln2_w, s_ff_up, ffbuf);
    ff2_k<<<4096, 320, 0, stream>>>(ffbuf, s_ff_dn, h);

    mlstm(1);
    mlstm(2);

    final_k<<<128, 256, 0, stream>>>(h, post_ln_w, out_w, out_b, (float*)d_out);
}

// Round 11
// 892.740 us; speedup vs baseline: 1.2480x; 1.1371x over previous
//
#include <hip/hip_runtime.h>
#include <math.h>

constexpr int cB = 128, cS = 256, cF = 10, cE = 40, cNH = 8, cDH = 5;
constexpr int cI = 128, cMDH = 16, cK = 4;

typedef __attribute__((ext_vector_type(8))) short short8v;   // 8 bf16 (4 VGPRs)
typedef __attribute__((ext_vector_type(4))) float f32x4;

#define BC8(v, l) __uint_as_float(__builtin_amdgcn_ds_swizzle(__float_as_uint(v), ((l) << 5) | 0x18))

__device__ __forceinline__ short f2bf(float f) {      // fp32 -> bf16 RTNE
    unsigned u = __float_as_uint(f);
    u += 0x7FFF + ((u >> 16) & 1);
    return (short)(u >> 16);
}

// ---------------- h = x @ in_w.T + in_b + pos_encoding ----------------
__global__ __launch_bounds__(256) void init_k(const float* __restrict__ x, const float* __restrict__ w,
                                              const float* __restrict__ b, float* __restrict__ h) {
    int idx = blockIdx.x * 256 + threadIdx.x;     // B*S*E
    int e = idx % cE; int bs = idx / cE; int s = bs % cS;
    float acc = b[e];
    const float* xr = x + (size_t)bs * cF;
#pragma unroll
    for (int f = 0; f < cF; ++f) acc += xr[f] * w[e * cF + f];
    int i2 = e >> 1;
    float div = expf(-(float)(2 * i2) * (logf(10000.f) / 40.0f));
    float arg = (float)s * div;
    acc += (e & 1) ? cosf(arg) : sinf(arg);
    h[idx] = acc;
}

// ---------------- fused LayerNorm + up-projection (E=40 -> 256) ----------------
__global__ __launch_bounds__(256) void ln_up_k(const float* __restrict__ h, const float* __restrict__ lnw,
                                               const float* __restrict__ upw, float* __restrict__ xmz) {
    __shared__ float lnr[8][cE];
    int row0 = blockIdx.x * 8;
    int tid = threadIdx.x;
    if (tid < 8) {
        const float* r = h + (size_t)(row0 + tid) * cE;
        float mu = 0.f;
        for (int k = 0; k < cE; ++k) mu += r[k];
        mu *= (1.f / cE);
        float va = 0.f;
        for (int k = 0; k < cE; ++k) { float d = r[k] - mu; va += d * d; }
        va *= (1.f / cE);
        float rs = rsqrtf(va + 1e-5f);
        for (int k = 0; k < cE; ++k) lnr[tid][k] = (r[k] - mu) * rs * lnw[k];
    }
    __syncthreads();
    int o = tid;   // 0..255
    float acc[8] = {0, 0, 0, 0, 0, 0, 0, 0};
    for (int k = 0; k < cE; ++k) {
        float wv = upw[o * cE + k];
#pragma unroll
        for (int r = 0; r < 8; ++r) acc[r] += lnr[r][k] * wv;
    }
#pragma unroll
    for (int r = 0; r < 8; ++r) xmz[(size_t)(row0 + r) * 256 + o] = acc[r];
}

// ---------------- depthwise causal conv (K=4) + SiLU ----------------
template <int C>
__global__ __launch_bounds__(256) void conv_silu_k(const float* __restrict__ in, int instride,
                                                   const float* __restrict__ w, const float* __restrict__ bias,
                                                   float* __restrict__ out) {
    int idx = blockIdx.x * 256 + threadIdx.x;   // B*S*C
    int c = idx % C; int bs = idx / C; int s = bs % cS;
    float acc = bias[c];
#pragma unroll
    for (int j = 0; j < cK; ++j) {
        int sj = s - 3 + j;
        if (sj >= 0) acc += in[(size_t)(bs + j - 3) * instride + c] * w[c * cK + j];
    }
    float sg = 1.f / (1.f + __expf(-acc));
    out[idx] = acc * sg;
}

// ---------------- block-diagonal headwise q,k,v ----------------
__global__ __launch_bounds__(256) void qkv_k(const float* __restrict__ xc, const float* __restrict__ xmz,
                                             const float* __restrict__ qw, const float* __restrict__ kw,
                                             const float* __restrict__ vw,
                                             float* __restrict__ qb, float* __restrict__ kb, float* __restrict__ vb) {
    int idx = blockIdx.x * 256 + threadIdx.x;   // B*S*I
    int c = idx & 127; int bs = idx >> 7;
    int n = c >> 2, o = c & 3;
    const float* xcr = xc + (size_t)bs * cI + n * 4;
    const float* xmr = xmz + (size_t)bs * 256 + n * 4;
    const float* qwp = qw + n * 16 + o * 4;
    const float* kwp = kw + n * 16 + o * 4;
    const float* vwp = vw + n * 16 + o * 4;
    float aq = 0, ak = 0, av = 0;
#pragma unroll
    for (int i = 0; i < 4; ++i) { float a = xcr[i], m = xmr[i]; aq += a * qwp[i]; ak += a * kwp[i]; av += m * vwp[i]; }
    qb[idx] = aq; kb[idx] = ak; vb[idx] = av;
}

// ---------------- input/forget gate pre-activations ip, fp (B,NH,S) v2 ----------------
__global__ __launch_bounds__(128, 2) void gates_k(const float* __restrict__ qb, const float* __restrict__ kb,
                                                  const float* __restrict__ vb, const float* __restrict__ igw,
                                                  const float* __restrict__ igb, const float* __restrict__ fgw,
                                                  const float* __restrict__ fgb,
                                                  float* __restrict__ ipb, float* __restrict__ fpb) {
    __shared__ float g[32 * 388];
    __shared__ float w[16 * 388];
    int row0 = blockIdx.x * 32;
    int tid = threadIdx.x;

    for (int i = tid; i < 16 * 96; i += 128) {
        int r = i / 96, c4 = i - r * 96;
        const float* src = (r < 8) ? (igw + r * 384) : (fgw + (r - 8) * 384);
        *(float4*)&w[r * 388 + c4 * 4] = ((const float4*)src)[c4];
    }
    for (int i = tid; i < 32 * 96; i += 128) {
        int r = i / 96, c4 = i - r * 96;
        size_t gr = (size_t)(row0 + r) * cI;
        const float4* src = (c4 < 32) ? (const float4*)(qb + gr) + c4
                          : (c4 < 64) ? (const float4*)(kb + gr) + (c4 - 32)
                                      : (const float4*)(vb + gr) + (c4 - 64);
        *(float4*)&g[r * 388 + c4 * 4] = *src;
    }
    __syncthreads();

    int rp = tid >> 3;
    int hp = tid & 7;
    int r0 = 2 * rp, r1 = r0 + 1;
    int o0 = 2 * hp, o1 = o0 + 1;

    const float4* g0p = (const float4*)(g + r0 * 388);
    const float4* g1p = (const float4*)(g + r1 * 388);
    const float4* w0p = (const float4*)(w + o0 * 388);
    const float4* w1p = (const float4*)(w + o1 * 388);

    float a00 = 0.f, a01 = 0.f, a10 = 0.f, a11 = 0.f;
#pragma unroll 4
    for (int c4 = 0; c4 < 96; ++c4) {
        float4 gv0 = g0p[c4], gv1 = g1p[c4];
        float4 wv0 = w0p[c4], wv1 = w1p[c4];
        a00 = fmaf(gv0.x, wv0.x, a00); a00 = fmaf(gv0.y, wv0.y, a00);
        a00 = fmaf(gv0.z, wv0.z, a00); a00 = fmaf(gv0.w, wv0.w, a00);
        a01 = fmaf(gv0.x, wv1.x, a01); a01 = fmaf(gv0.y, wv1.y, a01);
        a01 = fmaf(gv0.z, wv1.z, a01); a01 = fmaf(gv0.w, wv1.w, a01);
        a10 = fmaf(gv1.x, wv0.x, a10); a10 = fmaf(gv1.y, wv0.y, a10);
        a10 = fmaf(gv1.z, wv0.z, a10); a10 = fmaf(gv1.w, wv0.w, a10);
        a11 = fmaf(gv1.x, wv1.x, a11); a11 = fmaf(gv1.y, wv1.y, a11);
        a11 = fmaf(gv1.z, wv1.z, a11); a11 = fmaf(gv1.w, wv1.w, a11);
    }

    int h0 = o0 & 7, wch0 = o0 >> 3;
    int h1 = o1 & 7, wch1 = o1 >> 3;
    float b0 = wch0 ? fgb[h0] : igb[h0];
    float b1 = wch1 ? fgb[h1] : igb[h1];
    int grow0 = row0 + r0, grow1 = row0 + r1;
    int bb0 = grow0 >> 8, ss0 = grow0 & 255;
    int bb1 = grow1 >> 8, ss1 = grow1 & 255;
    float* d00 = (wch0 ? fpb : ipb) + (size_t)(bb0 * cNH + h0) * cS + ss0;
    float* d01 = (wch1 ? fpb : ipb) + (size_t)(bb0 * cNH + h1) * cS + ss0;
    float* d10 = (wch0 ? fpb : ipb) + (size_t)(bb1 * cNH + h0) * cS + ss1;
    float* d11 = (wch1 ? fpb : ipb) + (size_t)(bb1 * cNH + h1) * cS + ss1;
    *d00 = a00 + b0; *d01 = a01 + b1; *d10 = a10 + b0; *d11 = a11 + b1;
}

// ---------------- fused mLSTM attention v6: MFMA (bf16) ----------------
// One block (4 waves) per (b,h). Q,K,V converted to bf16 in LDS (V transposed).
// Per wave: 4 s-tiles; QK^T via mfma_f32_16x16x32_bf16 with K zero-padded to 32
// (slots g>=2 zero on BOTH operands -> correct under slot-pairing). Weighted,
// masked C tile -> bf16 LDS (per-wave, D-layout write / A-layout read = the
// transpose). PV + ones-MFMA (row sums for normalizer) accumulate in fp32.
// Layout facts used: A row = lane&15, B col = lane&15, D col=lane&15,
// row=(lane>>4)*4+j; k-slot map is pairing-invariant (same map both operands).
constexpr int QKW = 24;    // Qb/Kb row width (shorts): 48B rows, 16B-aligned
constexpr int VTW = 264;   // Vt row width
constexpr int CBW = 280;   // C row width

__global__ __launch_bounds__(256, 2) void attn_k(const float* __restrict__ qg, const float* __restrict__ kg,
                                                 const float* __restrict__ vg, const float* __restrict__ ipg,
                                                 const float* __restrict__ fpg, float* __restrict__ hatt) {
    int bh = blockIdx.x; int b = bh >> 3, h = bh & 7;
    int tid = threadIdx.x;
    int wid = tid >> 6, lane = tid & 63;
    int colL = lane & 15, grp = lane >> 4;

    __shared__ float sEA[cS], sMx[cS], sFc[cS];
    __shared__ short sQ[cS * QKW], sK[cS * QKW];
    __shared__ short sVt[cMDH * VTW];
    __shared__ short sC[4][16 * CBW];

    // --- gate scans (each wave computes redundantly; identical values) ---
    {
        const float4 fp4 = ((const float4*)(fpg + (size_t)bh * cS))[lane];
        const float4 ip4 = ((const float4*)(ipg + (size_t)bh * cS))[lane];
        float fpa[4] = {fp4.x, fp4.y, fp4.z, fp4.w};
        float ipa[4] = {ip4.x, ip4.y, ip4.z, ip4.w};
        float p[4];
        float run = 0.f;
#pragma unroll
        for (int i = 0; i < 4; ++i) {
            float xx = fpa[i];
            float lsg = fminf(xx, 0.f) - log1pf(expf(-fabsf(xx)));
            run += lsg; p[i] = run;
        }
        float cum = p[3];
#pragma unroll
        for (int off = 1; off < 64; off <<= 1) { float t = __shfl_up(cum, off); if (lane >= off) cum += t; }
        float excl = cum - p[3];
        float aa[4];
#pragma unroll
        for (int i = 0; i < 4; ++i) {
            float fcv = excl + p[i];
            aa[i] = ipa[i] - fcv;
            sFc[lane * 4 + i] = fcv;
            sEA[lane * 4 + i] = __expf(aa[i]);
        }
        float mq[4]; mq[0] = aa[0];
#pragma unroll
        for (int i = 1; i < 4; ++i) mq[i] = fmaxf(mq[i - 1], aa[i]);
        float cm = mq[3];
#pragma unroll
        for (int off = 1; off < 64; off <<= 1) { float t = __shfl_up(cm, off); if (lane >= off) cm = fmaxf(cm, t); }
        float exm = __shfl_up(cm, 1);
        if (lane == 0) exm = -3.0e38f;
#pragma unroll
        for (int i = 0; i < 4; ++i) sMx[lane * 4 + i] = fmaxf(exm, mq[i]);
    }

    // --- stage Q,K (bf16 row-major) and V^T (bf16) ---
    {
        int t = tid;
        const float4* qp = (const float4*)(qg + ((size_t)(b * cS) + t) * cI + h * cMDH);
        const float4* kp = (const float4*)(kg + ((size_t)(b * cS) + t) * cI + h * cMDH);
        const float4* vp = (const float4*)(vg + ((size_t)(b * cS) + t) * cI + h * cMDH);
        float4 q0 = qp[0], q1 = qp[1], q2 = qp[2], q3 = qp[3];
        float4 k0 = kp[0], k1 = kp[1], k2 = kp[2], k3 = kp[3];
        float4 v0 = vp[0], v1 = vp[1], v2 = vp[2], v3 = vp[3];
        short8v qa, qbv, ka, kbv;
        qa[0] = f2bf(q0.x); qa[1] = f2bf(q0.y); qa[2] = f2bf(q0.z); qa[3] = f2bf(q0.w);
        qa[4] = f2bf(q1.x); qa[5] = f2bf(q1.y); qa[6] = f2bf(q1.z); qa[7] = f2bf(q1.w);
        qbv[0] = f2bf(q2.x); qbv[1] = f2bf(q2.y); qbv[2] = f2bf(q2.z); qbv[3] = f2bf(q2.w);
        qbv[4] = f2bf(q3.x); qbv[5] = f2bf(q3.y); qbv[6] = f2bf(q3.z); qbv[7] = f2bf(q3.w);
        ka[0] = f2bf(k0.x); ka[1] = f2bf(k0.y); ka[2] = f2bf(k0.z); ka[3] = f2bf(k0.w);
        ka[4] = f2bf(k1.x); ka[5] = f2bf(k1.y); ka[6] = f2bf(k1.z); ka[7] = f2bf(k1.w);
        kbv[0] = f2bf(k2.x); kbv[1] = f2bf(k2.y); kbv[2] = f2bf(k2.z); kbv[3] = f2bf(k2.w);
        kbv[4] = f2bf(k3.x); kbv[5] = f2bf(k3.y); kbv[6] = f2bf(k3.z); kbv[7] = f2bf(k3.w);
        *(short8v*)(sQ + t * QKW) = qa;
        *(short8v*)(sQ + t * QKW + 8) = qbv;
        *(short8v*)(sK + t * QKW) = ka;
        *(short8v*)(sK + t * QKW + 8) = kbv;
        sVt[0 * VTW + t] = f2bf(v0.x);  sVt[1 * VTW + t] = f2bf(v0.y);
        sVt[2 * VTW + t] = f2bf(v0.z);  sVt[3 * VTW + t] = f2bf(v0.w);
        sVt[4 * VTW + t] = f2bf(v1.x);  sVt[5 * VTW + t] = f2bf(v1.y);
        sVt[6 * VTW + t] = f2bf(v1.z);  sVt[7 * VTW + t] = f2bf(v1.w);
        sVt[8 * VTW + t] = f2bf(v2.x);  sVt[9 * VTW + t] = f2bf(v2.y);
        sVt[10 * VTW + t] = f2bf(v2.z); sVt[11 * VTW + t] = f2bf(v2.w);
        sVt[12 * VTW + t] = f2bf(v3.x); sVt[13 * VTW + t] = f2bf(v3.y);
        sVt[14 * VTW + t] = f2bf(v3.z); sVt[15 * VTW + t] = f2bf(v3.w);
    }
    __syncthreads();

    const short one_bf = (short)0x3F80;
    short8v ones = {one_bf, one_bf, one_bf, one_bf, one_bf, one_bf, one_bf, one_bf};
    short8v kz = {0, 0, 0, 0, 0, 0, 0, 0};
    short* Cb = sC[wid];

    for (int sti = 0; sti < 4; ++sti) {
        int st = wid + sti * 4;          // s-tile 0..15
        int s0 = st * 16;

        float eMx4[4], flr4[4];
#pragma unroll
        for (int j = 0; j < 4; ++j) {
            int sg = s0 + grp * 4 + j;
            eMx4[j] = 0.25f * __expf(-sMx[sg]);
            flr4[j] = __expf(-(sFc[sg] + sMx[sg]));
        }

        // zero the PV over-read tile when (st+1) is odd
        if ((st & 1) == 0) {
#pragma unroll
            for (int z = 0; z < 4; ++z) {
                int idx = lane * 4 + z;
                Cb[(idx >> 4) * CBW + (st + 1) * 16 + (idx & 15)] = 0;
            }
        }

        // A = Q fragment for this s-tile (row = s0+colL, k-slots g*8+i; g>=2 zero)
        short8v aQ = (grp < 2) ? *(const short8v*)(sQ + (s0 + colL) * QKW + grp * 8) : kz;

        for (int tt = 0; tt <= st; ++tt) {
            int t0 = tt * 16;
            short8v bK = (grp < 2) ? *(const short8v*)(sK + (t0 + colL) * QKW + grp * 8) : kz;
            f32x4 zacc = {0.f, 0.f, 0.f, 0.f};
            f32x4 d = __builtin_amdgcn_mfma_f32_16x16x32_bf16(aQ, bK, zacc, 0, 0, 0);
            float ea = sEA[t0 + colL];
#pragma unroll
            for (int j = 0; j < 4; ++j) {
                float v = d[j] * (ea * eMx4[j]);
                if (tt == st) v = (colL <= grp * 4 + j) ? v : 0.f;
                Cb[(grp * 4 + j) * CBW + t0 + colL] = f2bf(v);
            }
        }

        __builtin_amdgcn_s_barrier();   // (wave-local Cb; barrier not strictly needed across waves,
                                        // but cheap ordering between Cb writes and reads on LDS path)
        f32x4 hacc = {0.f, 0.f, 0.f, 0.f};
        f32x4 sacc = {0.f, 0.f, 0.f, 0.f};
        int nch = (st + 2) >> 1;
        for (int c = 0; c < nch; ++c) {
            int tc = c * 32;
            short8v aC = *(const short8v*)(Cb + colL * CBW + tc + grp * 8);
            short8v bV = *(const short8v*)(sVt + colL * VTW + tc + grp * 8);
            hacc = __builtin_amdgcn_mfma_f32_16x16x32_bf16(aC, bV, hacc, 0, 0, 0);
            sacc = __builtin_amdgcn_mfma_f32_16x16x32_bf16(aC, ones, sacc, 0, 0, 0);
        }

#pragma unroll
        for (int j = 0; j < 4; ++j) {
            int sg = s0 + grp * 4 + j;
            float nrm = fmaxf(fabsf(sacc[j]), flr4[j]) + 1e-6f;
            hatt[((size_t)(b * cS) + sg) * cI + h * cMDH + colL] = hacc[j] / nrm;
        }
    }
}

// ---------------- fused multihead-norm + gate + down-projection + residual ----------------
__global__ __launch_bounds__(320) void down_mhn_k(const float* __restrict__ hatt, const float* __restrict__ xc,
                                                  const float* __restrict__ xmz, const float* __restrict__ mhnw,
                                                  const float* __restrict__ skip, const float* __restrict__ dw,
                                                  float* __restrict__ h) {
    __shared__ float yl[8 * 128];
    int row0 = blockIdx.x * 8;
    int tid = threadIdx.x;
    for (int i = tid; i < 1024; i += 320) yl[i] = hatt[(size_t)row0 * cI + i];
    __syncthreads();
    if (tid < 64) {
        int r = tid >> 3, hh = tid & 7;
        int row = row0 + r;
        float* g = yl + r * 128 + hh * 16;
        float xv[16];
        float mu = 0.f;
#pragma unroll
        for (int d = 0; d < 16; ++d) { xv[d] = g[d]; mu += xv[d]; }
        mu *= (1.f / 16);
        float va = 0.f;
#pragma unroll
        for (int d = 0; d < 16; ++d) { float dd = xv[d] - mu; va += dd * dd; }
        va *= (1.f / 16);
        float rs = rsqrtf(va + 1e-5f);
        const float* xcr = xc + (size_t)row * cI + hh * 16;
        const float* zr  = xmz + (size_t)row * 256 + 128 + hh * 16;
#pragma unroll
        for (int d = 0; d < 16; ++d) {
            int i = hh * 16 + d;
            float z = zr[d];
            float sg = 1.f / (1.f + __expf(-z));
            g[d] = ((xv[d] - mu) * rs * mhnw[i] + skip[i] * xcr[d]) * (z * sg);
        }
    }
    __syncthreads();
    int r = tid / 40, e = tid % 40;
    const float* dr = dw + e * cI;
    const float* yr = yl + r * cI;
    float acc = 0.f;
    for (int i = 0; i < cI; ++i) acc += yr[i] * dr[i];
    h[(size_t)(row0 + r) * cE + e] += acc;
}

// ---------------- plain row LayerNorm (E=40) ----------------
__global__ __launch_bounds__(256) void ln_rows_k(const float* __restrict__ h, const float* __restrict__ w,
                                                 float* __restrict__ out) {
    int rid = blockIdx.x * 256 + threadIdx.x;
    const float* r = h + (size_t)rid * cE;
    float mu = 0;
    for (int k = 0; k < cE; ++k) mu += r[k];
    mu *= (1.f / cE);
    float va = 0;
    for (int k = 0; k < cE; ++k) { float d = r[k] - mu; va += d * d; }
    va *= (1.f / cE);
    float rs = rsqrtf(va + 1e-5f);
    float* o = out + (size_t)rid * cE;
    for (int k = 0; k < cE; ++k) o[k] = (r[k] - mu) * rs * w[k];
}

// ---------------- sLSTM gate pre-activations; gall layout (S, B*NH, E=5, G=4) ----------------
__global__ __launch_bounds__(256) void sgates_k(const float* __restrict__ xcs, const float* __restrict__ ln1,
                                                const float* __restrict__ wi, const float* __restrict__ wf,
                                                const float* __restrict__ wz, const float* __restrict__ wo,
                                                float* __restrict__ gall) {
    int idx = blockIdx.x * 256 + threadIdx.x;   // S*1024*5*4
    int g = idx & 3; int r1 = idx >> 2;
    int e = r1 % 5; int r2 = r1 / 5;
    int bh = r2 & 1023; int s = r2 >> 10;
    int b = bh >> 3, h = bh & 7;
    const float* in = (g < 2) ? xcs : ln1;
    const float* w = (g == 0) ? wi : (g == 1) ? wf : (g == 2) ? wz : wo;
    const float* ir = in + ((size_t)(b * cS) + s) * cE + h * cDH;
    const float* wp = w + h * 25 + e * 5;
    float acc = 0.f;
#pragma unroll
    for (int i = 0; i < 5; ++i) acc += ir[i] * wp[i];
    gall[idx] = acc;
}

// ---------------- sLSTM sequential scan: 8 chains per wave ----------------
__global__ __launch_bounds__(64) void scan_k(const float* __restrict__ gall, const float* __restrict__ R,
                                             const float* __restrict__ bias, const float* __restrict__ mhnw,
                                             float* __restrict__ hbuf) {
    int lane = threadIdx.x;
    int grp = lane >> 3;
    int e = lane & 7;
    int ee = e < 5 ? e : 4;
    int bh = blockIdx.x * 8 + grp;
    int h = bh & 7;

    __shared__ float sOut[8][1285];

    float Rr[4][5];
#pragma unroll
    for (int g = 0; g < 4; ++g)
#pragma unroll
        for (int d = 0; d < 5; ++d) Rr[g][d] = R[h * 100 + g * 25 + d * 5 + ee];
    float bg[4];
#pragma unroll
    for (int g = 0; g < 4; ++g) bg[g] = bias[h * 20 + g * 5 + ee];
    float wmh = mhnw[h * 5 + ee];

    const float4* gp = (const float4*)gall + ((size_t)bh * 5 + ee);

    float4 rg[16];
#pragma unroll
    for (int j = 0; j < 16; ++j) rg[j] = gp[(size_t)j * 5120];

    float cstate = 0.f, nstate = 0.f, mstate = 0.f;
    float hs0 = 0.f, hs1 = 0.f, hs2 = 0.f, hs3 = 0.f, hs4 = 0.f;

    for (int t = 0; t < cS; t += 16) {
#pragma unroll
        for (int j = 0; j < 16; ++j) {
            float4 g4 = rg[j];
            rg[j] = gp[(size_t)(t + j + 16) * 5120];

            float ir = g4.x + bg[0], fr = g4.y + bg[1], zr = g4.z + bg[2], orr = g4.w + bg[3];
            ir = fmaf(hs0, Rr[0][0], ir); fr = fmaf(hs0, Rr[1][0], fr);
            zr = fmaf(hs0, Rr[2][0], zr); orr = fmaf(hs0, Rr[3][0], orr);
            ir = fmaf(hs1, Rr[0][1], ir); fr = fmaf(hs1, Rr[1][1], fr);
            zr = fmaf(hs1, Rr[2][1], zr); orr = fmaf(hs1, Rr[3][1], orr);
            ir = fmaf(hs2, Rr[0][2], ir); fr = fmaf(hs2, Rr[1][2], fr);
            zr = fmaf(hs2, Rr[2][2], zr); orr = fmaf(hs2, Rr[3][2], orr);
            ir = fmaf(hs3, Rr[0][3], ir); fr = fmaf(hs3, Rr[1][3], fr);
            zr = fmaf(hs3, Rr[2][3], zr); orr = fmaf(hs3, Rr[3][3], orr);
            ir = fmaf(hs4, Rr[0][4], ir); fr = fmaf(hs4, Rr[1][4], fr);
            zr = fmaf(hs4, Rr[2][4], zr); orr = fmaf(hs4, Rr[3][4], orr);

            float lsg = fminf(fr, 0.f) - __logf(1.f + __expf(-fabsf(fr)));
            float lfm = mstate + lsg;
            float mn = fmaxf(ir, lfm);
            float ig = __expf(ir - mn), fg = __expf(lfm - mn);
            float th = 1.f - 2.f * __builtin_amdgcn_rcpf(__expf(2.f * zr) + 1.f);
            float cn = fg * cstate + ig * th;
            float nn = fg * nstate + ig;
            float sg = __builtin_amdgcn_rcpf(1.f + __expf(-orr));
            float hn = sg * cn * __builtin_amdgcn_rcpf(nn);
            cstate = cn; nstate = nn; mstate = mn;

            hs0 = BC8(hn, 0); hs1 = BC8(hn, 1); hs2 = BC8(hn, 2);
            hs3 = BC8(hn, 3); hs4 = BC8(hn, 4);
            float mu = ((hs0 + hs1) + (hs2 + hs3) + hs4) * 0.2f;
            float d0 = hs0 - mu, d1 = hs1 - mu, d2 = hs2 - mu, d3 = hs3 - mu, d4 = hs4 - mu;
            float va = (d0 * d0 + d1 * d1 + d2 * d2 + d3 * d3 + d4 * d4) * 0.2f;
            float rs = __builtin_amdgcn_rsqf(va + 1e-5f);
            if (e < 5) sOut[grp][(t + j) * 5 + e] = (hn - mu) * rs * wmh;
        }
    }
    __syncthreads();

    for (int i = lane; i < 8 * 1280; i += 64) {
        int c = i / 1280;
        int r = i - c * 1280;
        int tt = r / 5, e2 = r - tt * 5;
        int bh2 = blockIdx.x * 8 + c;
        int b2 = bh2 >> 3, h2 = bh2 & 7;
        float* hp = hbuf + ((size_t)b2 * cS + tt) * cE + h2 * cDH + e2;
        *hp += sOut[c][r];
    }
}

// ---------------- FFN: fused LN + up-proj + exact GELU gate ----------------
__global__ __launch_bounds__(256) void ff1_k(const float* __restrict__ h, const float* __restrict__ lnw,
                                             const float* __restrict__ upw, float* __restrict__ ff) {
    __shared__ float lnr[4][cE];
    int row0 = blockIdx.x * 4;
    int tid = threadIdx.x;
    if (tid < 4) {
        const float* r = h + (size_t)(row0 + tid) * cE;
        float mu = 0;
        for (int k = 0; k < cE; ++k) mu += r[k];
        mu *= (1.f / cE);
        float va = 0;
        for (int k = 0; k < cE; ++k) { float d = r[k] - mu; va += d * d; }
        va *= (1.f / cE);
        float rs = rsqrtf(va + 1e-5f);
        for (int k = 0; k < cE; ++k) lnr[tid][k] = (r[k] - mu) * rs * lnw[k];
    }
    __syncthreads();
    int r = tid >> 6, f = tid & 63;
    float a = 0, u = 0;
    for (int k = 0; k < cE; ++k) {
        float xv = lnr[r][k];
        a += xv * upw[f * cE + k];
        u += xv * upw[(64 + f) * cE + k];
    }
    float g = 0.5f * a * (1.f + erff(a * 0.70710678118f));
    ff[(size_t)(row0 + r) * 64 + f] = g * u;
}

__global__ __launch_bounds__(320) void ff2_k(const float* __restrict__ ff, const float* __restrict__ dw,
                                             float* __restrict__ h) {
    __shared__ float fl[8 * 64];
    int row0 = blockIdx.x * 8;
    for (int i = threadIdx.x; i < 512; i += 320) fl[i] = ff[(size_t)row0 * 64 + i];
    __syncthreads();
    int r = threadIdx.x / 40, e = threadIdx.x % 40;
    const float* dr = dw + e * 64;
    const float* fr = fl + r * 64;
    float acc = 0.f;
    for (int i = 0; i < 64; ++i) acc += fr[i] * dr[i];
    h[(size_t)(row0 + r) * cE + e] += acc;
}

// ---------------- final LN + out projection ----------------
__global__ __launch_bounds__(256) void final_k(const float* __restrict__ h, const float* __restrict__ lnw,
                                               const float* __restrict__ ow, const float* __restrict__ ob,
                                               float* __restrict__ out) {
    int rid = blockIdx.x * 256 + threadIdx.x;
    const float* r = h + (size_t)rid * cE;
    float mu = 0;
    for (int k = 0; k < cE; ++k) mu += r[k];
    mu *= (1.f / cE);
    float va = 0;
    for (int k = 0; k < cE; ++k) { float d = r[k] - mu; va += d * d; }
    va *= (1.f / cE);
    float rs = rsqrtf(va + 1e-5f);
    float acc = ob[0];
    for (int k = 0; k < cE; ++k) acc += (r[k] - mu) * rs * lnw[k] * ow[k];
    out[rid] = acc;
}

extern "C" void kernel_launch(void* const* d_in, const int* in_sizes, int n_in,
                              void* d_out, int out_size, void* d_ws, size_t ws_size,
                              hipStream_t stream) {
    const float* x        = (const float*)d_in[0];
    const float* in_w     = (const float*)d_in[1];
    const float* in_b     = (const float*)d_in[2];
    const float* m_ln_w   = (const float*)d_in[3];
    const float* m_up_w   = (const float*)d_in[4];
    const float* m_conv_w = (const float*)d_in[5];
    const float* m_conv_b = (const float*)d_in[6];
    const float* m_q_w    = (const float*)d_in[7];
    const float* m_k_w    = (const float*)d_in[8];
    const float* m_v_w    = (const float*)d_in[9];
    const float* m_ig_w   = (const float*)d_in[10];
    const float* m_ig_b   = (const float*)d_in[11];
    const float* m_fg_w   = (const float*)d_in[12];
    const float* m_fg_b   = (const float*)d_in[13];
    const float* m_mhn_w  = (const float*)d_in[14];
    const float* m_skip   = (const float*)d_in[15];
    const float* m_down_w = (const float*)d_in[16];
    const float* s_ln1_w  = (const float*)d_in[17];
    const float* s_conv_w = (const float*)d_in[18];
    const float* s_conv_b = (const float*)d_in[19];
    const float* s_wi     = (const float*)d_in[20];
    const float* s_wf     = (const float*)d_in[21];
    const float* s_wz     = (const float*)d_in[22];
    const float* s_wo     = (const float*)d_in[23];
    const float* s_R      = (const float*)d_in[24];
    const float* s_bias   = (const float*)d_in[25];
    const float* s_mhn_w  = (const float*)d_in[26];
    const float* s_ln2_w  = (const float*)d_in[27];
    const float* s_ff_up  = (const float*)d_in[28];
    const float* s_ff_dn  = (const float*)d_in[29];
    const float* post_ln_w= (const float*)d_in[30];
    const float* out_w    = (const float*)d_in[31];
    const float* out_b    = (const float*)d_in[32];

    float* ws   = (float*)d_ws;
    float* h    = ws;                     // 1,310,720
    float* xmz  = h + 1310720;            // 8,388,608
    float* xc   = xmz + 8388608;          // 4,194,304
    float* qb   = xc + 4194304;           // 4,194,304
    float* kb   = qb + 4194304;           // 4,194,304
    float* vb   = kb + 4194304;           // 4,194,304
    float* ipb  = vb + 4194304;           //   262,144
    float* fpb  = ipb + 262144;           //   262,144
    float* hatt = fpb + 262144;           // 4,194,304
    float* lnbuf = xmz;
    float* xcs   = xmz + 1310720;
    float* gall  = xmz + 2621440;
    float* ffbuf = xmz;

    init_k<<<5120, 256, 0, stream>>>(x, in_w, in_b, h);

    auto mlstm = [&](int j) {
        ln_up_k<<<4096, 256, 0, stream>>>(h, m_ln_w + j * cE, m_up_w + (size_t)j * 256 * cE, xmz);
        conv_silu_k<128><<<16384, 256, 0, stream>>>(xmz, 256, m_conv_w + j * cI * cK, m_conv_b + j * cI, xc);
        qkv_k<<<16384, 256, 0, stream>>>(xc, xmz, m_q_w + j * 512, m_k_w + j * 512, m_v_w + j * 512, qb, kb, vb);
        gates_k<<<1024, 128, 0, stream>>>(qb, kb, vb, m_ig_w + j * cNH * 384, m_ig_b + j * cNH,
                                          m_fg_w + j * cNH * 384, m_fg_b + j * cNH, ipb, fpb);
        attn_k<<<1024, 256, 0, stream>>>(qb, kb, vb, ipb, fpb, hatt);
        down_mhn_k<<<4096, 320, 0, stream>>>(hatt, xc, xmz, m_mhn_w + j * cI, m_skip + j * cI,
                                             m_down_w + j * cE * cI, h);
    };

    mlstm(0);

    ln_rows_k<<<128, 256, 0, stream>>>(h, s_ln1_w, lnbuf);
    conv_silu_k<40><<<5120, 256, 0, stream>>>(lnbuf, 40, s_conv_w, s_conv_b, xcs);
    sgates_k<<<20480, 256, 0, stream>>>(xcs, lnbuf, s_wi, s_wf, s_wz, s_wo, gall);
    scan_k<<<128, 64, 0, stream>>>(gall, s_R, s_bias, s_mhn_w, h);

    ff1_k<<<8192, 256, 0, stream>>>(h, s_ln2_w, s_ff_up, ffbuf);
    ff2_k<<<4096, 320, 0, stream>>>(ffbuf, s_ff_dn, h);

    mlstm(1);
    mlstm(2);

    final_k<<<128, 256, 0, stream>>>(h, post_ln_w, out_w, out_b, (float*)d_out);
}

// Round 12
// 861.657 us; speedup vs baseline: 1.2930x; 1.0361x over previous
//
#include <hip/hip_runtime.h>
#include <math.h>

constexpr int cB = 128, cS = 256, cF = 10, cE = 40, cNH = 8, cDH = 5;
constexpr int cI = 128, cMDH = 16, cK = 4;

typedef __attribute__((ext_vector_type(8))) short short8v;   // 8 bf16 (4 VGPRs)
typedef __attribute__((ext_vector_type(4))) float f32x4;

#define BC8(v, l) __uint_as_float(__builtin_amdgcn_ds_swizzle(__float_as_uint(v), ((l) << 5) | 0x18))

__device__ __forceinline__ short f2bf(float f) {      // fp32 -> bf16 RTNE
    unsigned u = __float_as_uint(f);
    u += 0x7FFF + ((u >> 16) & 1);
    return (short)(u >> 16);
}

// ---------------- h = x @ in_w.T + in_b + pos_encoding ----------------
__global__ __launch_bounds__(256) void init_k(const float* __restrict__ x, const float* __restrict__ w,
                                              const float* __restrict__ b, float* __restrict__ h) {
    int idx = blockIdx.x * 256 + threadIdx.x;     // B*S*E
    int e = idx % cE; int bs = idx / cE; int s = bs % cS;
    float acc = b[e];
    const float* xr = x + (size_t)bs * cF;
#pragma unroll
    for (int f = 0; f < cF; ++f) acc += xr[f] * w[e * cF + f];
    int i2 = e >> 1;
    float div = expf(-(float)(2 * i2) * (logf(10000.f) / 40.0f));
    float arg = (float)s * div;
    acc += (e & 1) ? cosf(arg) : sinf(arg);
    h[idx] = acc;
}

// ---------------- fused LayerNorm + up-projection (E=40 -> 256) v2 ----------------
// 16 rows/block; upw staged TRANSPOSED in LDS (pad 257: staging writes and GEMV
// reads both bank-conflict-free; global loads coalesced float4). Was: per-thread
// stride-160 global scalar reads, 64 lines per wave-instruction.
__global__ __launch_bounds__(256) void ln_up_k(const float* __restrict__ h, const float* __restrict__ lnw,
                                               const float* __restrict__ upw, float* __restrict__ xmz) {
    __shared__ float lnr[16][cE];
    __shared__ float wT[cE * 257];
    int row0 = blockIdx.x * 16;
    int tid = threadIdx.x;
    for (int j = tid; j < 2560; j += 256) {       // 256*40/4 float4s
        float4 v = ((const float4*)upw)[j];
        int o = j / 10, kq = (j - o * 10) * 4;
        wT[(kq + 0) * 257 + o] = v.x;
        wT[(kq + 1) * 257 + o] = v.y;
        wT[(kq + 2) * 257 + o] = v.z;
        wT[(kq + 3) * 257 + o] = v.w;
    }
    if (tid < 16) {
        const float* r = h + (size_t)(row0 + tid) * cE;
        float mu = 0.f;
        for (int k = 0; k < cE; ++k) mu += r[k];
        mu *= (1.f / cE);
        float va = 0.f;
        for (int k = 0; k < cE; ++k) { float d = r[k] - mu; va += d * d; }
        va *= (1.f / cE);
        float rs = rsqrtf(va + 1e-5f);
        for (int k = 0; k < cE; ++k) lnr[tid][k] = (r[k] - mu) * rs * lnw[k];
    }
    __syncthreads();
    int o = tid;
    float acc[16];
#pragma unroll
    for (int r = 0; r < 16; ++r) acc[r] = 0.f;
    for (int k = 0; k < cE; ++k) {
        float wv = wT[k * 257 + o];
#pragma unroll
        for (int r = 0; r < 16; ++r) acc[r] = fmaf(lnr[r][k], wv, acc[r]);
    }
#pragma unroll
    for (int r = 0; r < 16; ++r) xmz[(size_t)(row0 + r) * 256 + o] = acc[r];
}

// ---------------- depthwise causal conv (K=4) + SiLU ----------------
template <int C>
__global__ __launch_bounds__(256) void conv_silu_k(const float* __restrict__ in, int instride,
                                                   const float* __restrict__ w, const float* __restrict__ bias,
                                                   float* __restrict__ out) {
    int idx = blockIdx.x * 256 + threadIdx.x;   // B*S*C
    int c = idx % C; int bs = idx / C; int s = bs % cS;
    float acc = bias[c];
#pragma unroll
    for (int j = 0; j < cK; ++j) {
        int sj = s - 3 + j;
        if (sj >= 0) acc += in[(size_t)(bs + j - 3) * instride + c] * w[c * cK + j];
    }
    float sg = 1.f / (1.f + __expf(-acc));
    out[idx] = acc * sg;
}

// ---------------- block-diagonal headwise q,k,v ----------------
__global__ __launch_bounds__(256) void qkv_k(const float* __restrict__ xc, const float* __restrict__ xmz,
                                             const float* __restrict__ qw, const float* __restrict__ kw,
                                             const float* __restrict__ vw,
                                             float* __restrict__ qb, float* __restrict__ kb, float* __restrict__ vb) {
    int idx = blockIdx.x * 256 + threadIdx.x;   // B*S*I
    int c = idx & 127; int bs = idx >> 7;
    int n = c >> 2, o = c & 3;
    const float* xcr = xc + (size_t)bs * cI + n * 4;
    const float* xmr = xmz + (size_t)bs * 256 + n * 4;
    const float* qwp = qw + n * 16 + o * 4;
    const float* kwp = kw + n * 16 + o * 4;
    const float* vwp = vw + n * 16 + o * 4;
    float aq = 0, ak = 0, av = 0;
#pragma unroll
    for (int i = 0; i < 4; ++i) { float a = xcr[i], m = xmr[i]; aq += a * qwp[i]; ak += a * kwp[i]; av += m * vwp[i]; }
    qb[idx] = aq; kb[idx] = ak; vb[idx] = av;
}

// ---------------- input/forget gate pre-activations ip, fp (B,NH,S) v3 ----------------
// 256 threads (was 128): 2 blocks/CU x 4 waves = 2 waves/SIMD so LDS-read latency
// of one wave hides under the other's FMA issue. 1 row x 2 outputs per thread,
// split accumulators keep 4 independent FMA chains.
__global__ __launch_bounds__(256, 2) void gates_k(const float* __restrict__ qb, const float* __restrict__ kb,
                                                  const float* __restrict__ vb, const float* __restrict__ igw,
                                                  const float* __restrict__ igb, const float* __restrict__ fgw,
                                                  const float* __restrict__ fgb,
                                                  float* __restrict__ ipb, float* __restrict__ fpb) {
    __shared__ float g[32 * 388];
    __shared__ float w[16 * 388];
    int row0 = blockIdx.x * 32;
    int tid = threadIdx.x;

    for (int i = tid; i < 16 * 96; i += 256) {
        int r = i / 96, c4 = i - r * 96;
        const float* src = (r < 8) ? (igw + r * 384) : (fgw + (r - 8) * 384);
        *(float4*)&w[r * 388 + c4 * 4] = ((const float4*)src)[c4];
    }
    for (int i = tid; i < 32 * 96; i += 256) {
        int r = i / 96, c4 = i - r * 96;
        size_t gr = (size_t)(row0 + r) * cI;
        const float4* src = (c4 < 32) ? (const float4*)(qb + gr) + c4
                          : (c4 < 64) ? (const float4*)(kb + gr) + (c4 - 32)
                                      : (const float4*)(vb + gr) + (c4 - 64);
        *(float4*)&g[r * 388 + c4 * 4] = *src;
    }
    __syncthreads();

    int rp = tid >> 3;              // row 0..31
    int hp = tid & 7;               // out-pair 0..7
    int o0 = 2 * hp, o1 = o0 + 1;

    const float4* gp = (const float4*)(g + rp * 388);
    const float4* w0p = (const float4*)(w + o0 * 388);
    const float4* w1p = (const float4*)(w + o1 * 388);

    float a0e = 0.f, a0o = 0.f, a1e = 0.f, a1o = 0.f;
#pragma unroll 2
    for (int c4 = 0; c4 < 96; c4 += 2) {
        float4 gv0 = gp[c4], gv1 = gp[c4 + 1];
        float4 wa0 = w0p[c4], wa1 = w0p[c4 + 1];
        float4 wb0 = w1p[c4], wb1 = w1p[c4 + 1];
        a0e = fmaf(gv0.x, wa0.x, a0e); a0e = fmaf(gv0.y, wa0.y, a0e);
        a0e = fmaf(gv0.z, wa0.z, a0e); a0e = fmaf(gv0.w, wa0.w, a0e);
        a1e = fmaf(gv0.x, wb0.x, a1e); a1e = fmaf(gv0.y, wb0.y, a1e);
        a1e = fmaf(gv0.z, wb0.z, a1e); a1e = fmaf(gv0.w, wb0.w, a1e);
        a0o = fmaf(gv1.x, wa1.x, a0o); a0o = fmaf(gv1.y, wa1.y, a0o);
        a0o = fmaf(gv1.z, wa1.z, a0o); a0o = fmaf(gv1.w, wa1.w, a0o);
        a1o = fmaf(gv1.x, wb1.x, a1o); a1o = fmaf(gv1.y, wb1.y, a1o);
        a1o = fmaf(gv1.z, wb1.z, a1o); a1o = fmaf(gv1.w, wb1.w, a1o);
    }
    float a0 = a0e + a0o, a1 = a1e + a1o;

    int h0 = o0 & 7, wch0 = o0 >> 3;
    int h1 = o1 & 7, wch1 = o1 >> 3;
    float b0 = wch0 ? fgb[h0] : igb[h0];
    float b1 = wch1 ? fgb[h1] : igb[h1];
    int grow = row0 + rp;
    int bb = grow >> 8, ss = grow & 255;
    float* d0 = (wch0 ? fpb : ipb) + (size_t)(bb * cNH + h0) * cS + ss;
    float* d1 = (wch1 ? fpb : ipb) + (size_t)(bb * cNH + h1) * cS + ss;
    *d0 = a0 + b0; *d1 = a1 + b1;
}

// ---------------- fused mLSTM attention v7: MFMA (bf16), balanced tiles ----------------
// One block (4 waves) per (b,h). Wave w handles s-tiles {w, 7-w, 8+w, 15-w}
// (34 tt-iterations each: balanced triangle). Cb is wave-private -> no block
// barrier in the tile loop (compiler's lgkmcnt ordering covers LDS RAW).
constexpr int QKW = 24;    // Qb/Kb row width (shorts)
constexpr int VTW = 264;   // Vt row width
constexpr int CBW = 280;   // C row width

__global__ __launch_bounds__(256, 2) void attn_k(const float* __restrict__ qg, const float* __restrict__ kg,
                                                 const float* __restrict__ vg, const float* __restrict__ ipg,
                                                 const float* __restrict__ fpg, float* __restrict__ hatt) {
    int bh = blockIdx.x; int b = bh >> 3, h = bh & 7;
    int tid = threadIdx.x;
    int wid = tid >> 6, lane = tid & 63;
    int colL = lane & 15, grp = lane >> 4;

    __shared__ float sEA[cS], sMx[cS], sFc[cS];
    __shared__ short sQ[cS * QKW], sK[cS * QKW];
    __shared__ short sVt[cMDH * VTW];
    __shared__ short sC[4][16 * CBW];

    // --- gate scans (each wave computes redundantly; identical values) ---
    {
        const float4 fp4 = ((const float4*)(fpg + (size_t)bh * cS))[lane];
        const float4 ip4 = ((const float4*)(ipg + (size_t)bh * cS))[lane];
        float fpa[4] = {fp4.x, fp4.y, fp4.z, fp4.w};
        float ipa[4] = {ip4.x, ip4.y, ip4.z, ip4.w};
        float p[4];
        float run = 0.f;
#pragma unroll
        for (int i = 0; i < 4; ++i) {
            float xx = fpa[i];
            float lsg = fminf(xx, 0.f) - log1pf(expf(-fabsf(xx)));
            run += lsg; p[i] = run;
        }
        float cum = p[3];
#pragma unroll
        for (int off = 1; off < 64; off <<= 1) { float t = __shfl_up(cum, off); if (lane >= off) cum += t; }
        float excl = cum - p[3];
        float aa[4];
#pragma unroll
        for (int i = 0; i < 4; ++i) {
            float fcv = excl + p[i];
            aa[i] = ipa[i] - fcv;
            sFc[lane * 4 + i] = fcv;
            sEA[lane * 4 + i] = __expf(aa[i]);
        }
        float mq[4]; mq[0] = aa[0];
#pragma unroll
        for (int i = 1; i < 4; ++i) mq[i] = fmaxf(mq[i - 1], aa[i]);
        float cm = mq[3];
#pragma unroll
        for (int off = 1; off < 64; off <<= 1) { float t = __shfl_up(cm, off); if (lane >= off) cm = fmaxf(cm, t); }
        float exm = __shfl_up(cm, 1);
        if (lane == 0) exm = -3.0e38f;
#pragma unroll
        for (int i = 0; i < 4; ++i) sMx[lane * 4 + i] = fmaxf(exm, mq[i]);
    }

    // --- stage Q,K (bf16 row-major) and V^T (bf16) ---
    {
        int t = tid;
        const float4* qp = (const float4*)(qg + ((size_t)(b * cS) + t) * cI + h * cMDH);
        const float4* kp = (const float4*)(kg + ((size_t)(b * cS) + t) * cI + h * cMDH);
        const float4* vp = (const float4*)(vg + ((size_t)(b * cS) + t) * cI + h * cMDH);
        float4 q0 = qp[0], q1 = qp[1], q2 = qp[2], q3 = qp[3];
        float4 k0 = kp[0], k1 = kp[1], k2 = kp[2], k3 = kp[3];
        float4 v0 = vp[0], v1 = vp[1], v2 = vp[2], v3 = vp[3];
        short8v qa, qbv, ka, kbv;
        qa[0] = f2bf(q0.x); qa[1] = f2bf(q0.y); qa[2] = f2bf(q0.z); qa[3] = f2bf(q0.w);
        qa[4] = f2bf(q1.x); qa[5] = f2bf(q1.y); qa[6] = f2bf(q1.z); qa[7] = f2bf(q1.w);
        qbv[0] = f2bf(q2.x); qbv[1] = f2bf(q2.y); qbv[2] = f2bf(q2.z); qbv[3] = f2bf(q2.w);
        qbv[4] = f2bf(q3.x); qbv[5] = f2bf(q3.y); qbv[6] = f2bf(q3.z); qbv[7] = f2bf(q3.w);
        ka[0] = f2bf(k0.x); ka[1] = f2bf(k0.y); ka[2] = f2bf(k0.z); ka[3] = f2bf(k0.w);
        ka[4] = f2bf(k1.x); ka[5] = f2bf(k1.y); ka[6] = f2bf(k1.z); ka[7] = f2bf(k1.w);
        kbv[0] = f2bf(k2.x); kbv[1] = f2bf(k2.y); kbv[2] = f2bf(k2.z); kbv[3] = f2bf(k2.w);
        kbv[4] = f2bf(k3.x); kbv[5] = f2bf(k3.y); kbv[6] = f2bf(k3.z); kbv[7] = f2bf(k3.w);
        *(short8v*)(sQ + t * QKW) = qa;
        *(short8v*)(sQ + t * QKW + 8) = qbv;
        *(short8v*)(sK + t * QKW) = ka;
        *(short8v*)(sK + t * QKW + 8) = kbv;
        sVt[0 * VTW + t] = f2bf(v0.x);  sVt[1 * VTW + t] = f2bf(v0.y);
        sVt[2 * VTW + t] = f2bf(v0.z);  sVt[3 * VTW + t] = f2bf(v0.w);
        sVt[4 * VTW + t] = f2bf(v1.x);  sVt[5 * VTW + t] = f2bf(v1.y);
        sVt[6 * VTW + t] = f2bf(v1.z);  sVt[7 * VTW + t] = f2bf(v1.w);
        sVt[8 * VTW + t] = f2bf(v2.x);  sVt[9 * VTW + t] = f2bf(v2.y);
        sVt[10 * VTW + t] = f2bf(v2.z); sVt[11 * VTW + t] = f2bf(v2.w);
        sVt[12 * VTW + t] = f2bf(v3.x); sVt[13 * VTW + t] = f2bf(v3.y);
        sVt[14 * VTW + t] = f2bf(v3.z); sVt[15 * VTW + t] = f2bf(v3.w);
    }
    __syncthreads();

    const short one_bf = (short)0x3F80;
    short8v ones = {one_bf, one_bf, one_bf, one_bf, one_bf, one_bf, one_bf, one_bf};
    short8v kz = {0, 0, 0, 0, 0, 0, 0, 0};
    short* Cb = sC[wid];
    const int tiles[4] = {wid, 7 - wid, 8 + wid, 15 - wid};   // balanced triangle

    for (int sti = 0; sti < 4; ++sti) {
        int st = tiles[sti];
        int s0 = st * 16;

        float eMx4[4], flr4[4];
#pragma unroll
        for (int j = 0; j < 4; ++j) {
            int sg = s0 + grp * 4 + j;
            eMx4[j] = 0.25f * __expf(-sMx[sg]);
            flr4[j] = __expf(-(sFc[sg] + sMx[sg]));
        }

        // zero the PV over-read tile when PV reads one tile past st
        if ((st & 1) == 0) {
#pragma unroll
            for (int z = 0; z < 4; ++z) {
                int idx = lane * 4 + z;
                Cb[(idx >> 4) * CBW + (st + 1) * 16 + (idx & 15)] = 0;
            }
        }

        short8v aQ = (grp < 2) ? *(const short8v*)(sQ + (s0 + colL) * QKW + grp * 8) : kz;

        for (int tt = 0; tt <= st; ++tt) {
            int t0 = tt * 16;
            short8v bK = (grp < 2) ? *(const short8v*)(sK + (t0 + colL) * QKW + grp * 8) : kz;
            f32x4 zacc = {0.f, 0.f, 0.f, 0.f};
            f32x4 d = __builtin_amdgcn_mfma_f32_16x16x32_bf16(aQ, bK, zacc, 0, 0, 0);
            float ea = sEA[t0 + colL];
#pragma unroll
            for (int j = 0; j < 4; ++j) {
                float v = d[j] * (ea * eMx4[j]);
                if (tt == st) v = (colL <= grp * 4 + j) ? v : 0.f;
                Cb[(grp * 4 + j) * CBW + t0 + colL] = f2bf(v);
            }
        }

        f32x4 hacc = {0.f, 0.f, 0.f, 0.f};
        f32x4 sacc = {0.f, 0.f, 0.f, 0.f};
        int nch = (st + 2) >> 1;
        for (int c = 0; c < nch; ++c) {
            int tc = c * 32;
            short8v aC = *(const short8v*)(Cb + colL * CBW + tc + grp * 8);
            short8v bV = *(const short8v*)(sVt + colL * VTW + tc + grp * 8);
            hacc = __builtin_amdgcn_mfma_f32_16x16x32_bf16(aC, bV, hacc, 0, 0, 0);
            sacc = __builtin_amdgcn_mfma_f32_16x16x32_bf16(aC, ones, sacc, 0, 0, 0);
        }

#pragma unroll
        for (int j = 0; j < 4; ++j) {
            int sg = s0 + grp * 4 + j;
            float nrm = fmaxf(fabsf(sacc[j]), flr4[j]) + 1e-6f;
            hatt[((size_t)(b * cS) + sg) * cI + h * cMDH + colL] = hacc[j] / nrm;
        }
    }
}

// ---------------- fused multihead-norm + gate + down-projection + residual ----------------
__global__ __launch_bounds__(320) void down_mhn_k(const float* __restrict__ hatt, const float* __restrict__ xc,
                                                  const float* __restrict__ xmz, const float* __restrict__ mhnw,
                                                  const float* __restrict__ skip, const float* __restrict__ dw,
                                                  float* __restrict__ h) {
    __shared__ float yl[8 * 128];
    int row0 = blockIdx.x * 8;
    int tid = threadIdx.x;
    for (int i = tid; i < 1024; i += 320) yl[i] = hatt[(size_t)row0 * cI + i];
    __syncthreads();
    if (tid < 64) {
        int r = tid >> 3, hh = tid & 7;
        int row = row0 + r;
        float* g = yl + r * 128 + hh * 16;
        float xv[16];
        float mu = 0.f;
#pragma unroll
        for (int d = 0; d < 16; ++d) { xv[d] = g[d]; mu += xv[d]; }
        mu *= (1.f / 16);
        float va = 0.f;
#pragma unroll
        for (int d = 0; d < 16; ++d) { float dd = xv[d] - mu; va += dd * dd; }
        va *= (1.f / 16);
        float rs = rsqrtf(va + 1e-5f);
        const float* xcr = xc + (size_t)row * cI + hh * 16;
        const float* zr  = xmz + (size_t)row * 256 + 128 + hh * 16;
#pragma unroll
        for (int d = 0; d < 16; ++d) {
            int i = hh * 16 + d;
            float z = zr[d];
            float sg = 1.f / (1.f + __expf(-z));
            g[d] = ((xv[d] - mu) * rs * mhnw[i] + skip[i] * xcr[d]) * (z * sg);
        }
    }
    __syncthreads();
    int r = tid / 40, e = tid % 40;
    const float* dr = dw + e * cI;
    const float* yr = yl + r * cI;
    float acc = 0.f;
    for (int i = 0; i < cI; ++i) acc += yr[i] * dr[i];
    h[(size_t)(row0 + r) * cE + e] += acc;
}

// ---------------- plain row LayerNorm (E=40) ----------------
__global__ __launch_bounds__(256) void ln_rows_k(const float* __restrict__ h, const float* __restrict__ w,
                                                 float* __restrict__ out) {
    int rid = blockIdx.x * 256 + threadIdx.x;
    const float* r = h + (size_t)rid * cE;
    float mu = 0;
    for (int k = 0; k < cE; ++k) mu += r[k];
    mu *= (1.f / cE);
    float va = 0;
    for (int k = 0; k < cE; ++k) { float d = r[k] - mu; va += d * d; }
    va *= (1.f / cE);
    float rs = rsqrtf(va + 1e-5f);
    float* o = out + (size_t)rid * cE;
    for (int k = 0; k < cE; ++k) o[k] = (r[k] - mu) * rs * w[k];
}

// ---------------- sLSTM gate pre-activations; gall layout (S, B*NH, E=5, G=4) ----------------
__global__ __launch_bounds__(256) void sgates_k(const float* __restrict__ xcs, const float* __restrict__ ln1,
                                                const float* __restrict__ wi, const float* __restrict__ wf,
                                                const float* __restrict__ wz, const float* __restrict__ wo,
                                                float* __restrict__ gall) {
    int idx = blockIdx.x * 256 + threadIdx.x;   // S*1024*5*4
    int g = idx & 3; int r1 = idx >> 2;
    int e = r1 % 5; int r2 = r1 / 5;
    int bh = r2 & 1023; int s = r2 >> 10;
    int b = bh >> 3, h = bh & 7;
    const float* in = (g < 2) ? xcs : ln1;
    const float* w = (g == 0) ? wi : (g == 1) ? wf : (g == 2) ? wz : wo;
    const float* ir = in + ((size_t)(b * cS) + s) * cE + h * cDH;
    const float* wp = w + h * 25 + e * 5;
    float acc = 0.f;
#pragma unroll
    for (int i = 0; i < 5; ++i) acc += ir[i] * wp[i];
    gall[idx] = acc;
}

// ---------------- sLSTM sequential scan: 8 chains per wave ----------------
__global__ __launch_bounds__(64) void scan_k(const float* __restrict__ gall, const float* __restrict__ R,
                                             const float* __restrict__ bias, const float* __restrict__ mhnw,
                                             float* __restrict__ hbuf) {
    int lane = threadIdx.x;
    int grp = lane >> 3;
    int e = lane & 7;
    int ee = e < 5 ? e : 4;
    int bh = blockIdx.x * 8 + grp;
    int h = bh & 7;

    __shared__ float sOut[8][1285];

    float Rr[4][5];
#pragma unroll
    for (int g = 0; g < 4; ++g)
#pragma unroll
        for (int d = 0; d < 5; ++d) Rr[g][d] = R[h * 100 + g * 25 + d * 5 + ee];
    float bg[4];
#pragma unroll
    for (int g = 0; g < 4; ++g) bg[g] = bias[h * 20 + g * 5 + ee];
    float wmh = mhnw[h * 5 + ee];

    const float4* gp = (const float4*)gall + ((size_t)bh * 5 + ee);

    float4 rg[16];
#pragma unroll
    for (int j = 0; j < 16; ++j) rg[j] = gp[(size_t)j * 5120];

    float cstate = 0.f, nstate = 0.f, mstate = 0.f;
    float hs0 = 0.f, hs1 = 0.f, hs2 = 0.f, hs3 = 0.f, hs4 = 0.f;

    for (int t = 0; t < cS; t += 16) {
#pragma unroll
        for (int j = 0; j < 16; ++j) {
            float4 g4 = rg[j];
            rg[j] = gp[(size_t)(t + j + 16) * 5120];

            float ir = g4.x + bg[0], fr = g4.y + bg[1], zr = g4.z + bg[2], orr = g4.w + bg[3];
            ir = fmaf(hs0, Rr[0][0], ir); fr = fmaf(hs0, Rr[1][0], fr);
            zr = fmaf(hs0, Rr[2][0], zr); orr = fmaf(hs0, Rr[3][0], orr);
            ir = fmaf(hs1, Rr[0][1], ir); fr = fmaf(hs1, Rr[1][1], fr);
            zr = fmaf(hs1, Rr[2][1], zr); orr = fmaf(hs1, Rr[3][1], orr);
            ir = fmaf(hs2, Rr[0][2], ir); fr = fmaf(hs2, Rr[1][2], fr);
            zr = fmaf(hs2, Rr[2][2], zr); orr = fmaf(hs2, Rr[3][2], orr);
            ir = fmaf(hs3, Rr[0][3], ir); fr = fmaf(hs3, Rr[1][3], fr);
            zr = fmaf(hs3, Rr[2][3], zr); orr = fmaf(hs3, Rr[3][3], orr);
            ir = fmaf(hs4, Rr[0][4], ir); fr = fmaf(hs4, Rr[1][4], fr);
            zr = fmaf(hs4, Rr[2][4], zr); orr = fmaf(hs4, Rr[3][4], orr);

            float lsg = fminf(fr, 0.f) - __logf(1.f + __expf(-fabsf(fr)));
            float lfm = mstate + lsg;
            float mn = fmaxf(ir, lfm);
            float ig = __expf(ir - mn), fg = __expf(lfm - mn);
            float th = 1.f - 2.f * __builtin_amdgcn_rcpf(__expf(2.f * zr) + 1.f);
            float cn = fg * cstate + ig * th;
            float nn = fg * nstate + ig;
            float sg = __builtin_amdgcn_rcpf(1.f + __expf(-orr));
            float hn = sg * cn * __builtin_amdgcn_rcpf(nn);
            cstate = cn; nstate = nn; mstate = mn;

            hs0 = BC8(hn, 0); hs1 = BC8(hn, 1); hs2 = BC8(hn, 2);
            hs3 = BC8(hn, 3); hs4 = BC8(hn, 4);
            float mu = ((hs0 + hs1) + (hs2 + hs3) + hs4) * 0.2f;
            float d0 = hs0 - mu, d1 = hs1 - mu, d2 = hs2 - mu, d3 = hs3 - mu, d4 = hs4 - mu;
            float va = (d0 * d0 + d1 * d1 + d2 * d2 + d3 * d3 + d4 * d4) * 0.2f;
            float rs = __builtin_amdgcn_rsqf(va + 1e-5f);
            if (e < 5) sOut[grp][(t + j) * 5 + e] = (hn - mu) * rs * wmh;
        }
    }
    __syncthreads();

    for (int i = lane; i < 8 * 1280; i += 64) {
        int c = i / 1280;
        int r = i - c * 1280;
        int tt = r / 5, e2 = r - tt * 5;
        int bh2 = blockIdx.x * 8 + c;
        int b2 = bh2 >> 3, h2 = bh2 & 7;
        float* hp = hbuf + ((size_t)b2 * cS + tt) * cE + h2 * cDH + e2;
        *hp += sOut[c][r];
    }
}

// ---------------- FFN: fused LN + up-proj + exact GELU gate ----------------
__global__ __launch_bounds__(256) void ff1_k(const float* __restrict__ h, const float* __restrict__ lnw,
                                             const float* __restrict__ upw, float* __restrict__ ff) {
    __shared__ float lnr[4][cE];
    int row0 = blockIdx.x * 4;
    int tid = threadIdx.x;
    if (tid < 4) {
        const float* r = h + (size_t)(row0 + tid) * cE;
        float mu = 0;
        for (int k = 0; k < cE; ++k) mu += r[k];
        mu *= (1.f / cE);
        float va = 0;
        for (int k = 0; k < cE; ++k) { float d = r[k] - mu; va += d * d; }
        va *= (1.f / cE);
        float rs = rsqrtf(va + 1e-5f);
        for (int k = 0; k < cE; ++k) lnr[tid][k] = (r[k] - mu) * rs * lnw[k];
    }
    __syncthreads();
    int r = tid >> 6, f = tid & 63;
    float a = 0, u = 0;
    for (int k = 0; k < cE; ++k) {
        float xv = lnr[r][k];
        a += xv * upw[f * cE + k];
        u += xv * upw[(64 + f) * cE + k];
    }
    float g = 0.5f * a * (1.f + erff(a * 0.70710678118f));
    ff[(size_t)(row0 + r) * 64 + f] = g * u;
}

__global__ __launch_bounds__(320) void ff2_k(const float* __restrict__ ff, const float* __restrict__ dw,
                                             float* __restrict__ h) {
    __shared__ float fl[8 * 64];
    int row0 = blockIdx.x * 8;
    for (int i = threadIdx.x; i < 512; i += 320) fl[i] = ff[(size_t)row0 * 64 + i];
    __syncthreads();
    int r = threadIdx.x / 40, e = threadIdx.x % 40;
    const float* dr = dw + e * 64;
    const float* fr = fl + r * 64;
    float acc = 0.f;
    for (int i = 0; i < 64; ++i) acc += fr[i] * dr[i];
    h[(size_t)(row0 + r) * cE + e] += acc;
}

// ---------------- final LN + out projection ----------------
__global__ __launch_bounds__(256) void final_k(const float* __restrict__ h, const float* __restrict__ lnw,
                                               const float* __restrict__ ow, const float* __restrict__ ob,
                                               float* __restrict__ out) {
    int rid = blockIdx.x * 256 + threadIdx.x;
    const float* r = h + (size_t)rid * cE;
    float mu = 0;
    for (int k = 0; k < cE; ++k) mu += r[k];
    mu *= (1.f / cE);
    float va = 0;
    for (int k = 0; k < cE; ++k) { float d = r[k] - mu; va += d * d; }
    va *= (1.f / cE);
    float rs = rsqrtf(va + 1e-5f);
    float acc = ob[0];
    for (int k = 0; k < cE; ++k) acc += (r[k] - mu) * rs * lnw[k] * ow[k];
    out[rid] = acc;
}

extern "C" void kernel_launch(void* const* d_in, const int* in_sizes, int n_in,
                              void* d_out, int out_size, void* d_ws, size_t ws_size,
                              hipStream_t stream) {
    const float* x        = (const float*)d_in[0];
    const float* in_w     = (const float*)d_in[1];
    const float* in_b     = (const float*)d_in[2];
    const float* m_ln_w   = (const float*)d_in[3];
    const float* m_up_w   = (const float*)d_in[4];
    const float* m_conv_w = (const float*)d_in[5];
    const float* m_conv_b = (const float*)d_in[6];
    const float* m_q_w    = (const float*)d_in[7];
    const float* m_k_w    = (const float*)d_in[8];
    const float* m_v_w    = (const float*)d_in[9];
    const float* m_ig_w   = (const float*)d_in[10];
    const float* m_ig_b   = (const float*)d_in[11];
    const float* m_fg_w   = (const float*)d_in[12];
    const float* m_fg_b   = (const float*)d_in[13];
    const float* m_mhn_w  = (const float*)d_in[14];
    const float* m_skip   = (const float*)d_in[15];
    const float* m_down_w = (const float*)d_in[16];
    const float* s_ln1_w  = (const float*)d_in[17];
    const float* s_conv_w = (const float*)d_in[18];
    const float* s_conv_b = (const float*)d_in[19];
    const float* s_wi     = (const float*)d_in[20];
    const float* s_wf     = (const float*)d_in[21];
    const float* s_wz     = (const float*)d_in[22];
    const float* s_wo     = (const float*)d_in[23];
    const float* s_R      = (const float*)d_in[24];
    const float* s_bias   = (const float*)d_in[25];
    const float* s_mhn_w  = (const float*)d_in[26];
    const float* s_ln2_w  = (const float*)d_in[27];
    const float* s_ff_up  = (const float*)d_in[28];
    const float* s_ff_dn  = (const float*)d_in[29];
    const float* post_ln_w= (const float*)d_in[30];
    const float* out_w    = (const float*)d_in[31];
    const float* out_b    = (const float*)d_in[32];

    float* ws   = (float*)d_ws;
    float* h    = ws;                     // 1,310,720
    float* xmz  = h + 1310720;            // 8,388,608
    float* xc   = xmz + 8388608;          // 4,194,304
    float* qb   = xc + 4194304;           // 4,194,304
    float* kb   = qb + 4194304;           // 4,194,304
    float* vb   = kb + 4194304;           // 4,194,304
    float* ipb  = vb + 4194304;           //   262,144
    float* fpb  = ipb + 262144;           //   262,144
    float* hatt = fpb + 262144;           // 4,194,304
    float* lnbuf = xmz;
    float* xcs   = xmz + 1310720;
    float* gall  = xmz + 2621440;
    float* ffbuf = xmz;

    init_k<<<5120, 256, 0, stream>>>(x, in_w, in_b, h);

    auto mlstm = [&](int j) {
        ln_up_k<<<2048, 256, 0, stream>>>(h, m_ln_w + j * cE, m_up_w + (size_t)j * 256 * cE, xmz);
        conv_silu_k<128><<<16384, 256, 0, stream>>>(xmz, 256, m_conv_w + j * cI * cK, m_conv_b + j * cI, xc);
        qkv_k<<<16384, 256, 0, stream>>>(xc, xmz, m_q_w + j * 512, m_k_w + j * 512, m_v_w + j * 512, qb, kb, vb);
        gates_k<<<1024, 256, 0, stream>>>(qb, kb, vb, m_ig_w + j * cNH * 384, m_ig_b + j * cNH,
                                          m_fg_w + j * cNH * 384, m_fg_b + j * cNH, ipb, fpb);
        attn_k<<<1024, 256, 0, stream>>>(qb, kb, vb, ipb, fpb, hatt);
        down_mhn_k<<<4096, 320, 0, stream>>>(hatt, xc, xmz, m_mhn_w + j * cI, m_skip + j * cI,
                                             m_down_w + j * cE * cI, h);
    };

    mlstm(0);

    ln_rows_k<<<128, 256, 0, stream>>>(h, s_ln1_w, lnbuf);
    conv_silu_k<40><<<5120, 256, 0, stream>>>(lnbuf, 40, s_conv_w, s_conv_b, xcs);
    sgates_k<<<20480, 256, 0, stream>>>(xcs, lnbuf, s_wi, s_wf, s_wz, s_wo, gall);
    scan_k<<<128, 64, 0, stream>>>(gall, s_R, s_bias, s_mhn_w, h);

    ff1_k<<<8192, 256, 0, stream>>>(h, s_ln2_w, s_ff_up, ffbuf);
    ff2_k<<<4096, 320, 0, stream>>>(ffbuf, s_ff_dn, h);

    mlstm(1);
    mlstm(2);

    final_k<<<128, 256, 0, stream>>>(h, post_ln_w, out_w, out_b, (float*)d_out);
}